// Round 2
// baseline (1801.257 us; speedup 1.0000x reference)
//
#include <hip/hip_runtime.h>

// ---------------------------------------------------------------------------
// SRU (2-layer bidirectional, v2 cell) + fc head for MI355X (gfx950).
// Pipeline per call (single U buffer, reused 4x):
//   1. cast x (f32 -> bf16)
//   2. transpose+cast 4 weight matrices W[K=1024][N=1536] -> Wt[N][K] bf16
//   3. per (layer, dir): GEMM U = A @ W (bf16 MFMA, fp32 acc) ; chunked scan
//   4. fc head (fp32, wave shuffle-reduce)
// Workspace-adaptive: U stored f32 if it fits ws_size, else bf16.
// ---------------------------------------------------------------------------

#define T_LEN 16384
#define D_IN 1024
#define HDIM 512
#define NC 15
#define NU 1536          // 3*H columns in U
#define CHUNK 512
#define WARM 256
#define NCHUNK (T_LEN / CHUNK)

typedef __attribute__((ext_vector_type(8))) short short8v;
typedef __attribute__((ext_vector_type(4))) float float4v;
typedef __attribute__((ext_vector_type(4))) int int4v;

__device__ __forceinline__ unsigned short f2bf(float f) {
    unsigned u = __float_as_uint(f);
    unsigned r = (u + 0x7FFFu + ((u >> 16) & 1u)) >> 16;
    return (unsigned short)r;
}
__device__ __forceinline__ float bf2f(unsigned short s) {
    return __uint_as_float(((unsigned)s) << 16);
}
__device__ __forceinline__ float ldx(const float* p) { return *p; }
__device__ __forceinline__ float ldx(const unsigned short* p) { return bf2f(*p); }

__device__ __forceinline__ void stc(float* p, float v) { *p = v; }
__device__ __forceinline__ void stc(unsigned short* p, float v) { *p = f2bf(v); }

__device__ __forceinline__ float sigm(float x) {
    return 1.0f / (1.0f + __expf(-x));
}

// -------------------------- cast x to bf16 ---------------------------------
__global__ __launch_bounds__(256) void cast_f32_bf16(const float* __restrict__ in,
                                                     unsigned short* __restrict__ out,
                                                     long n) {
    long i = ((long)blockIdx.x * blockDim.x + threadIdx.x) * 4;
    if (i + 3 < n) {
        float4v v = *(const float4v*)(in + i);
        unsigned short o0 = f2bf(v[0]), o1 = f2bf(v[1]), o2 = f2bf(v[2]), o3 = f2bf(v[3]);
        unsigned short* p = out + i;
        p[0] = o0; p[1] = o1; p[2] = o2; p[3] = o3;
    }
}

// ---------------- transpose + cast weights: [K][N] f32 -> [N][K] bf16 ------
__global__ __launch_bounds__(256) void transpose_cast(const float* __restrict__ w,
                                                      unsigned short* __restrict__ wt,
                                                      int K, int N) {
    __shared__ float tile[32][33];
    int n0 = blockIdx.x * 32, k0 = blockIdx.y * 32;
    int tx = threadIdx.x;   // 0..31
    int ty = threadIdx.y;   // 0..7
#pragma unroll
    for (int i = 0; i < 32; i += 8)
        tile[ty + i][tx] = w[(size_t)(k0 + ty + i) * N + n0 + tx];
    __syncthreads();
#pragma unroll
    for (int i = 0; i < 32; i += 8)
        wt[(size_t)(n0 + ty + i) * K + k0 + tx] = f2bf(tile[tx][ty + i]);
}

// ------------------------------ MFMA GEMM ----------------------------------
// C[M][N] = A[M][K] bf16 @ Wt[N][K] bf16 (i.e. W[K][N]), K = 1024.
// 128x128 tile, BK=64, 256 thr (4 waves, 2x2), each wave 64x64 = 4x4 frags.
// LDS XOR-swizzled (chunk ^= row&7) on both write and read -> conflict-free.
#define BM 128
#define BN 128
#define BK 64

template <typename CT>
__global__ __launch_bounds__(256) void gemm_bf16(const unsigned short* __restrict__ A,
                                                 const unsigned short* __restrict__ B,
                                                 CT* __restrict__ C,
                                                 int M, int N, int K) {
    __shared__ int4v lds[(BM * BK + BN * BK) * 2 / 16];
    char* ldsA = (char*)lds;
    char* ldsB = (char*)lds + BM * BK * 2;

    int tid = threadIdx.x;
    int m0 = blockIdx.x * BM;
    int n0 = blockIdx.y * BN;
    int wid = tid >> 6, lane = tid & 63;
    int wm = (wid >> 1) * 64, wn = (wid & 1) * 64;
    int l15 = lane & 15, l4 = lane >> 4;

    float4v acc[4][4] = {};

    for (int kt = 0; kt < K; kt += BK) {
        int4v av[4], bv[4];
#pragma unroll
        for (int i = 0; i < 4; i++) {
            int c = tid + i * 256;
            int row = c >> 3, cc = c & 7;
            av[i] = *(const int4v*)(A + (size_t)(m0 + row) * K + kt + cc * 8);
            bv[i] = *(const int4v*)(B + (size_t)(n0 + row) * K + kt + cc * 8);
        }
        __syncthreads();
#pragma unroll
        for (int i = 0; i < 4; i++) {
            int c = tid + i * 256;
            int row = c >> 3, cc = c & 7;
            int sw = (cc ^ (row & 7)) * 16;
            *(int4v*)(ldsA + row * 128 + sw) = av[i];
            *(int4v*)(ldsB + row * 128 + sw) = bv[i];
        }
        __syncthreads();
#pragma unroll
        for (int ks = 0; ks < 2; ks++) {
            short8v af[4], bfr[4];
#pragma unroll
            for (int f = 0; f < 4; f++) {
                int ra = wm + f * 16 + l15;
                int ca = ((ks * 4 + l4) ^ (ra & 7)) * 16;
                af[f] = *(const short8v*)(ldsA + ra * 128 + ca);
                int rb = wn + f * 16 + l15;
                int cb = ((ks * 4 + l4) ^ (rb & 7)) * 16;
                bfr[f] = *(const short8v*)(ldsB + rb * 128 + cb);
            }
#pragma unroll
            for (int fm = 0; fm < 4; fm++)
#pragma unroll
                for (int fn = 0; fn < 4; fn++)
                    acc[fm][fn] = __builtin_amdgcn_mfma_f32_16x16x32_bf16(
                        af[fm], bfr[fn], acc[fm][fn], 0, 0, 0);
        }
    }
    // epilogue: D[row=(l>>4)*4+j][col=l&15] per 16x16 frag (m89-verified layout)
#pragma unroll
    for (int fm = 0; fm < 4; fm++) {
        int r0 = m0 + wm + fm * 16 + l4 * 4;
#pragma unroll
        for (int fn = 0; fn < 4; fn++) {
            int c0 = n0 + wn + fn * 16 + l15;
#pragma unroll
            for (int j = 0; j < 4; j++)
                stc(&C[(size_t)(r0 + j) * N + c0], acc[fm][fn][j]);
        }
    }
}

// ------------------------------ SRU scan -----------------------------------
// One direction per launch (U buffer is shared/reused). Each block = 64
// channels x 1 chunk. Warm-up WARM steps before the chunk (gate product
// decays ~e^-200 -> exact to fp32). 8-deep register-ring prefetch.
template <typename UT, typename XT>
__global__ __launch_bounds__(64) void sru_scan(const UT* __restrict__ U,
                                               const XT* __restrict__ xr,
                                               const float* __restrict__ vv,
                                               const float* __restrict__ bb,
                                               unsigned short* __restrict__ hout,
                                               int dir, int outbase) {
    int ch = blockIdx.x * 64 + threadIdx.x;
    int cid = blockIdx.y;
    int outc = outbase + ch;

    float vfv = vv[ch], vrv = vv[HDIM + ch];
    float bfv = bb[ch], brv = bb[HDIM + ch];

    int cb = cid * CHUNK;
    int tstart, N;
    if (dir == 0) {
        tstart = cb - WARM; if (tstart < 0) tstart = 0;
        N = cb + CHUNK - tstart;
    } else {
        tstart = cb + CHUNK - 1 + WARM; if (tstart > T_LEN - 1) tstart = T_LEN - 1;
        N = tstart - cb + 1;
    }

    constexpr int D = 8;
    float r0[D], r1[D], r2[D], rx[D];
#pragma unroll
    for (int d = 0; d < D; d++) {
        if (d < N) {
            int t = dir ? tstart - d : tstart + d;
            size_t bi = (size_t)t * NU + ch;
            r0[d] = ldx(U + bi); r1[d] = ldx(U + bi + HDIM); r2[d] = ldx(U + bi + 2 * HDIM);
            rx[d] = ldx(xr + (size_t)t * D_IN + ch);
        }
    }

    float c = 0.0f;
    for (int nb = 0; nb < N; nb += D) {
#pragma unroll
        for (int d = 0; d < D; d++) {
            int n = nb + d;
            if (n < N) {
                int t = dir ? tstart - n : tstart + n;
                float u0 = r0[d], u1 = r1[d], u2 = r2[d], xv = rx[d];
                int np = n + D;
                if (np < N) {  // prefetch D steps ahead into this slot
                    int tp = dir ? tstart - np : tstart + np;
                    size_t bi = (size_t)tp * NU + ch;
                    r0[d] = ldx(U + bi); r1[d] = ldx(U + bi + HDIM); r2[d] = ldx(U + bi + 2 * HDIM);
                    rx[d] = ldx(xr + (size_t)tp * D_IN + ch);
                }
                float g1 = sigm(u1 + vfv * c + bfv);
                c = g1 * c + (1.0f - g1) * u0;
                float g2 = sigm(u2 + vrv * c + brv);
                float h = g2 * c + (1.0f - g2) * xv;
                bool wr = dir ? (t <= cb + CHUNK - 1) : (t >= cb);
                if (wr) hout[(size_t)t * D_IN + outc] = f2bf(h);
            }
        }
    }
}

// ------------------------------ fc head ------------------------------------
// out[T][15] = h1[T][1024] @ fc_w[1024][15] + fc_b. One wave per 4 rows;
// lane covers k = lane*16 .. +16; shuffle-reduce over 64 lanes.
__global__ __launch_bounds__(256) void fc_kernel(const unsigned short* __restrict__ h,
                                                 const float* __restrict__ W,
                                                 const float* __restrict__ bias,
                                                 float* __restrict__ out) {
    int gwid = (int)((blockIdx.x * (size_t)blockDim.x + threadIdx.x) >> 6);
    int lane = threadIdx.x & 63;
    int r0 = gwid * 4;
    int k0 = lane * 16;

    float hv[4][16];
#pragma unroll
    for (int r = 0; r < 4; r++) {
#pragma unroll
        for (int i = 0; i < 16; i += 8) {
            short8v v = *(const short8v*)(h + (size_t)(r0 + r) * D_IN + k0 + i);
#pragma unroll
            for (int j = 0; j < 8; j++)
                hv[r][i + j] = bf2f((unsigned short)v[j]);
        }
    }
    float acc[4][NC];
#pragma unroll
    for (int r = 0; r < 4; r++)
#pragma unroll
        for (int cdx = 0; cdx < NC; cdx++) acc[r][cdx] = 0.0f;

#pragma unroll
    for (int i = 0; i < 16; i++) {
        const float* wrow = W + (size_t)(k0 + i) * NC;
#pragma unroll
        for (int cdx = 0; cdx < NC; cdx++) {
            float wv = wrow[cdx];
            acc[0][cdx] += hv[0][i] * wv;
            acc[1][cdx] += hv[1][i] * wv;
            acc[2][cdx] += hv[2][i] * wv;
            acc[3][cdx] += hv[3][i] * wv;
        }
    }
#pragma unroll
    for (int r = 0; r < 4; r++)
#pragma unroll
        for (int cdx = 0; cdx < NC; cdx++) {
            float s = acc[r][cdx];
#pragma unroll
            for (int m = 1; m < 64; m <<= 1) s += __shfl_xor(s, m, 64);
            acc[r][cdx] = s;
        }
#pragma unroll
    for (int r = 0; r < 4; r++) {
        float val = 0.0f;
#pragma unroll
        for (int cdx = 0; cdx < NC; cdx++)
            if (lane == cdx) val = acc[r][cdx];
        if (lane < NC) out[(size_t)(r0 + r) * NC + lane] = val + bias[lane];
    }
}

// ------------------------------ launcher -----------------------------------
extern "C" void kernel_launch(void* const* d_in, const int* in_sizes, int n_in,
                              void* d_out, int out_size, void* d_ws, size_t ws_size,
                              hipStream_t stream) {
    const float* x    = (const float*)d_in[0];
    const float* w0f  = (const float*)d_in[1];
    const float* v0f  = (const float*)d_in[2];
    const float* b0f  = (const float*)d_in[3];
    const float* w0b  = (const float*)d_in[4];
    const float* v0b  = (const float*)d_in[5];
    const float* b0b  = (const float*)d_in[6];
    const float* w1f  = (const float*)d_in[7];
    const float* v1f  = (const float*)d_in[8];
    const float* b1f  = (const float*)d_in[9];
    const float* w1b  = (const float*)d_in[10];
    const float* v1b  = (const float*)d_in[11];
    const float* b1b  = (const float*)d_in[12];
    const float* fcw  = (const float*)d_in[13];
    const float* fcb  = (const float*)d_in[14];
    float* out = (float*)d_out;

    char* ws = (char*)d_ws;
    const size_t XB_B  = (size_t)T_LEN * D_IN * 2;   // 33.5 MB (also h1)
    const size_t WT_B  = (size_t)NU * D_IN * 2;      // 3.15 MB each
    const size_t H0_B  = (size_t)T_LEN * D_IN * 2;   // 33.5 MB
    const size_t U32_B = (size_t)T_LEN * NU * 4;     // 100.7 MB
    const size_t U16_B = (size_t)T_LEN * NU * 2;     //  50.3 MB

    size_t off = 0;
    unsigned short* xb   = (unsigned short*)(ws + off); off += XB_B;
    unsigned short* h1   = xb;                            // alias: xb dead after layer-0 GEMMs
    unsigned short* wt0f = (unsigned short*)(ws + off); off += WT_B;
    unsigned short* wt0b = (unsigned short*)(ws + off); off += WT_B;
    unsigned short* wt1f = (unsigned short*)(ws + off); off += WT_B;
    unsigned short* wt1b = (unsigned short*)(ws + off); off += WT_B;
    unsigned short* h0   = (unsigned short*)(ws + off); off += H0_B;
    void* Uraw = (void*)(ws + off);
    bool u_f32 = (off + U32_B) <= ws_size;   // adaptive: f32 U if it fits

    // 1. casts / transposes
    cast_f32_bf16<<<T_LEN * D_IN / 4 / 256, 256, 0, stream>>>(x, xb, (long)T_LEN * D_IN);
    dim3 tb(32, 8);
    dim3 tg(NU / 32, D_IN / 32);
    transpose_cast<<<tg, tb, 0, stream>>>(w0f, wt0f, D_IN, NU);
    transpose_cast<<<tg, tb, 0, stream>>>(w0b, wt0b, D_IN, NU);
    transpose_cast<<<tg, tb, 0, stream>>>(w1f, wt1f, D_IN, NU);
    transpose_cast<<<tg, tb, 0, stream>>>(w1b, wt1b, D_IN, NU);

    dim3 gg(T_LEN / BM, NU / BN);
    dim3 sg(HDIM / 64, NCHUNK, 1);

    if (u_f32) {
        float* U = (float*)Uraw;
        // layer 0
        gemm_bf16<float><<<gg, 256, 0, stream>>>(xb, wt0f, U, T_LEN, NU, D_IN);
        sru_scan<float, float><<<sg, 64, 0, stream>>>(U, x, v0f, b0f, h0, 0, 0);
        gemm_bf16<float><<<gg, 256, 0, stream>>>(xb, wt0b, U, T_LEN, NU, D_IN);
        sru_scan<float, float><<<sg, 64, 0, stream>>>(U, x + HDIM, v0b, b0b, h0, 1, HDIM);
        // layer 1 (h1 aliases xb; xb no longer read)
        gemm_bf16<float><<<gg, 256, 0, stream>>>(h0, wt1f, U, T_LEN, NU, D_IN);
        sru_scan<float, unsigned short><<<sg, 64, 0, stream>>>(U, h0, v1f, b1f, h1, 0, 0);
        gemm_bf16<float><<<gg, 256, 0, stream>>>(h0, wt1b, U, T_LEN, NU, D_IN);
        sru_scan<float, unsigned short><<<sg, 64, 0, stream>>>(U, h0 + HDIM, v1b, b1b, h1, 1, HDIM);
    } else {
        unsigned short* U = (unsigned short*)Uraw;
        gemm_bf16<unsigned short><<<gg, 256, 0, stream>>>(xb, wt0f, U, T_LEN, NU, D_IN);
        sru_scan<unsigned short, float><<<sg, 64, 0, stream>>>(U, x, v0f, b0f, h0, 0, 0);
        gemm_bf16<unsigned short><<<gg, 256, 0, stream>>>(xb, wt0b, U, T_LEN, NU, D_IN);
        sru_scan<unsigned short, float><<<sg, 64, 0, stream>>>(U, x + HDIM, v0b, b0b, h0, 1, HDIM);
        gemm_bf16<unsigned short><<<gg, 256, 0, stream>>>(h0, wt1f, U, T_LEN, NU, D_IN);
        sru_scan<unsigned short, unsigned short><<<sg, 64, 0, stream>>>(U, h0, v1f, b1f, h1, 0, 0);
        gemm_bf16<unsigned short><<<gg, 256, 0, stream>>>(h0, wt1b, U, T_LEN, NU, D_IN);
        sru_scan<unsigned short, unsigned short><<<sg, 64, 0, stream>>>(U, h0 + HDIM, v1b, b1b, h1, 1, HDIM);
    }

    // 4. fc head
    fc_kernel<<<T_LEN / 4 * 64 / 256, 256, 0, stream>>>(h1, fcw, fcb, out);
    (void)in_sizes; (void)n_in; (void)out_size;
}

// Round 3
// 546.291 us; speedup vs baseline: 3.2972x; 3.2972x over previous
//
#include <hip/hip_runtime.h>

// ---------------------------------------------------------------------------
// SRU (2-layer bidirectional, v2 cell) + fc head for MI355X (gfx950).
//   1. cast x (f32 -> bf16)
//   2. transpose+cast 4 weight matrices W[K=1024][N=1536] -> Wt[N][K] bf16
//   3. per layer: GEMM Uf, GEMM Ub (bf16 out) ; one scan launch (both dirs)
//   4. fc head
// Scan: CHUNK=128, WARM=128 -> 2048 waves (8/CU), warm loop loads only u0,u1.
// ---------------------------------------------------------------------------

#define T_LEN 16384
#define D_IN 1024
#define HDIM 512
#define NC 15
#define NU 1536          // 3*H columns in U
#define CHUNK 128
#define WARM 128
#define NCHUNK (T_LEN / CHUNK)   // 128

typedef __attribute__((ext_vector_type(8))) short short8v;
typedef __attribute__((ext_vector_type(4))) float float4v;
typedef __attribute__((ext_vector_type(4))) int int4v;

__device__ __forceinline__ unsigned short f2bf(float f) {
    unsigned u = __float_as_uint(f);
    unsigned r = (u + 0x7FFFu + ((u >> 16) & 1u)) >> 16;
    return (unsigned short)r;
}
__device__ __forceinline__ float bf2f(unsigned short s) {
    return __uint_as_float(((unsigned)s) << 16);
}
__device__ __forceinline__ float ldx(const float* p) { return *p; }
__device__ __forceinline__ float ldx(const unsigned short* p) { return bf2f(*p); }

__device__ __forceinline__ void stc(float* p, float v) { *p = v; }
__device__ __forceinline__ void stc(unsigned short* p, float v) { *p = f2bf(v); }

__device__ __forceinline__ float sigm(float x) {
    float e = __expf(-x);
    return __builtin_amdgcn_rcpf(1.0f + e);
}

// -------------------------- cast x to bf16 ---------------------------------
__global__ __launch_bounds__(256) void cast_f32_bf16(const float* __restrict__ in,
                                                     unsigned short* __restrict__ out,
                                                     long n) {
    long i = ((long)blockIdx.x * blockDim.x + threadIdx.x) * 4;
    if (i + 3 < n) {
        float4v v = *(const float4v*)(in + i);
        unsigned short o0 = f2bf(v[0]), o1 = f2bf(v[1]), o2 = f2bf(v[2]), o3 = f2bf(v[3]);
        unsigned short* p = out + i;
        p[0] = o0; p[1] = o1; p[2] = o2; p[3] = o3;
    }
}

// ---------------- transpose + cast weights: [K][N] f32 -> [N][K] bf16 ------
__global__ __launch_bounds__(256) void transpose_cast(const float* __restrict__ w,
                                                      unsigned short* __restrict__ wt,
                                                      int K, int N) {
    __shared__ float tile[32][33];
    int n0 = blockIdx.x * 32, k0 = blockIdx.y * 32;
    int tx = threadIdx.x;   // 0..31
    int ty = threadIdx.y;   // 0..7
#pragma unroll
    for (int i = 0; i < 32; i += 8)
        tile[ty + i][tx] = w[(size_t)(k0 + ty + i) * N + n0 + tx];
    __syncthreads();
#pragma unroll
    for (int i = 0; i < 32; i += 8)
        wt[(size_t)(n0 + ty + i) * K + k0 + tx] = f2bf(tile[tx][ty + i]);
}

// ------------------------------ MFMA GEMM ----------------------------------
// C[M][N] = A[M][K] bf16 @ Wt[N][K] bf16 (i.e. W[K][N]), K = 1024.
// 128x128 tile, BK=64, 256 thr (4 waves, 2x2), each wave 64x64 = 4x4 frags.
// LDS XOR-swizzled (chunk ^= row&7) on both write and read -> conflict-free.
#define BM 128
#define BN 128
#define BK 64

template <typename CT>
__global__ __launch_bounds__(256) void gemm_bf16(const unsigned short* __restrict__ A,
                                                 const unsigned short* __restrict__ B,
                                                 CT* __restrict__ C,
                                                 int M, int N, int K) {
    __shared__ int4v lds[(BM * BK + BN * BK) * 2 / 16];
    char* ldsA = (char*)lds;
    char* ldsB = (char*)lds + BM * BK * 2;

    int tid = threadIdx.x;
    int m0 = blockIdx.x * BM;
    int n0 = blockIdx.y * BN;
    int wid = tid >> 6, lane = tid & 63;
    int wm = (wid >> 1) * 64, wn = (wid & 1) * 64;
    int l15 = lane & 15, l4 = lane >> 4;

    float4v acc[4][4] = {};

    for (int kt = 0; kt < K; kt += BK) {
        int4v av[4], bv[4];
#pragma unroll
        for (int i = 0; i < 4; i++) {
            int c = tid + i * 256;
            int row = c >> 3, cc = c & 7;
            av[i] = *(const int4v*)(A + (size_t)(m0 + row) * K + kt + cc * 8);
            bv[i] = *(const int4v*)(B + (size_t)(n0 + row) * K + kt + cc * 8);
        }
        __syncthreads();
#pragma unroll
        for (int i = 0; i < 4; i++) {
            int c = tid + i * 256;
            int row = c >> 3, cc = c & 7;
            int sw = (cc ^ (row & 7)) * 16;
            *(int4v*)(ldsA + row * 128 + sw) = av[i];
            *(int4v*)(ldsB + row * 128 + sw) = bv[i];
        }
        __syncthreads();
#pragma unroll
        for (int ks = 0; ks < 2; ks++) {
            short8v af[4], bfr[4];
#pragma unroll
            for (int f = 0; f < 4; f++) {
                int ra = wm + f * 16 + l15;
                int ca = ((ks * 4 + l4) ^ (ra & 7)) * 16;
                af[f] = *(const short8v*)(ldsA + ra * 128 + ca);
                int rb = wn + f * 16 + l15;
                int cb = ((ks * 4 + l4) ^ (rb & 7)) * 16;
                bfr[f] = *(const short8v*)(ldsB + rb * 128 + cb);
            }
#pragma unroll
            for (int fm = 0; fm < 4; fm++)
#pragma unroll
                for (int fn = 0; fn < 4; fn++)
                    acc[fm][fn] = __builtin_amdgcn_mfma_f32_16x16x32_bf16(
                        af[fm], bfr[fn], acc[fm][fn], 0, 0, 0);
        }
    }
    // epilogue: D[row=(l>>4)*4+j][col=l&15] per 16x16 frag (m89-verified layout)
#pragma unroll
    for (int fm = 0; fm < 4; fm++) {
        int r0 = m0 + wm + fm * 16 + l4 * 4;
#pragma unroll
        for (int fn = 0; fn < 4; fn++) {
            int c0 = n0 + wn + fn * 16 + l15;
#pragma unroll
            for (int j = 0; j < 4; j++)
                stc(&C[(size_t)(r0 + j) * N + c0], acc[fm][fn][j]);
        }
    }
}

// ------------------------------ SRU scan -----------------------------------
// Both directions in one launch (grid.z = 2). Each block = 64 channels x
// 1 chunk x 1 dir; 2048 blocks -> 8 waves/CU. Warm-up WARM steps (u0,u1 only,
// gate product decays ~e^-100 -> exact). 8-deep register-ring prefetch.
template <typename XT>
__global__ __launch_bounds__(64) void sru_scan(const unsigned short* __restrict__ Uf,
                                               const unsigned short* __restrict__ Ub,
                                               const XT* __restrict__ xrf,
                                               const XT* __restrict__ xrb,
                                               const float* __restrict__ vF,
                                               const float* __restrict__ bF,
                                               const float* __restrict__ vB,
                                               const float* __restrict__ bB,
                                               unsigned short* __restrict__ hout) {
    int dir = blockIdx.z;
    int ch = blockIdx.x * 64 + threadIdx.x;
    int cid = blockIdx.y;

    const unsigned short* U;
    const XT* xr;
    const float* vv;
    const float* bb;
    int outc;
    if (dir == 0) { U = Uf; xr = xrf; vv = vF; bb = bF; outc = ch; }
    else          { U = Ub; xr = xrb; vv = vB; bb = bB; outc = HDIM + ch; }

    float vfv = vv[ch], vrv = vv[HDIM + ch];
    float bfv = bb[ch], brv = bb[HDIM + ch];

    int cb = cid * CHUNK;
    int mstart = dir ? cb + CHUNK - 1 : cb;   // first main-phase timestep
    int wstart, wn;                           // warm-up phase
    if (dir == 0) {
        wstart = cb - WARM; if (wstart < 0) wstart = 0;
        wn = cb - wstart;
    } else {
        wstart = cb + CHUNK - 1 + WARM; if (wstart > T_LEN - 1) wstart = T_LEN - 1;
        wn = wstart - (cb + CHUNK - 1);
    }

    constexpr int D = 8;
    // main-phase ring: issue these loads FIRST so they're deep in flight
    float m0[D], m1[D], m2[D], mx[D];
#pragma unroll
    for (int d = 0; d < D; d++) {
        int t = dir ? mstart - d : mstart + d;
        size_t bi = (size_t)t * NU + ch;
        m0[d] = bf2f(U[bi]); m1[d] = bf2f(U[bi + HDIM]); m2[d] = bf2f(U[bi + 2 * HDIM]);
        mx[d] = ldx(xr + (size_t)t * D_IN + ch);
    }
    // warm-phase ring (u0,u1 only)
    float w0[D], w1[D];
#pragma unroll
    for (int d = 0; d < D; d++) {
        if (d < wn) {
            int t = dir ? wstart - d : wstart + d;
            size_t bi = (size_t)t * NU + ch;
            w0[d] = bf2f(U[bi]); w1[d] = bf2f(U[bi + HDIM]);
        }
    }

    float c = 0.0f;
    // warm-up: state only (wn is uniform across the wave)
    for (int nb = 0; nb < wn; nb += D) {
#pragma unroll
        for (int d = 0; d < D; d++) {
            int n = nb + d;
            if (n < wn) {
                float u0 = w0[d], u1 = w1[d];
                int np = n + D;
                if (np < wn) {
                    int tp = dir ? wstart - np : wstart + np;
                    size_t bi = (size_t)tp * NU + ch;
                    w0[d] = bf2f(U[bi]); w1[d] = bf2f(U[bi + HDIM]);
                }
                float g1 = sigm(u1 + vfv * c + bfv);
                c = g1 * c + (1.0f - g1) * u0;
            }
        }
    }
    // main: full cell + h write (exactly CHUNK steps)
    for (int nb = 0; nb < CHUNK; nb += D) {
#pragma unroll
        for (int d = 0; d < D; d++) {
            int n = nb + d;
            int t = dir ? mstart - n : mstart + n;
            float u0 = m0[d], u1 = m1[d], u2 = m2[d], xv = mx[d];
            int np = n + D;
            if (np < CHUNK) {
                int tp = dir ? mstart - np : mstart + np;
                size_t bi = (size_t)tp * NU + ch;
                m0[d] = bf2f(U[bi]); m1[d] = bf2f(U[bi + HDIM]); m2[d] = bf2f(U[bi + 2 * HDIM]);
                mx[d] = ldx(xr + (size_t)tp * D_IN + ch);
            }
            float g1 = sigm(u1 + vfv * c + bfv);
            c = g1 * c + (1.0f - g1) * u0;
            float g2 = sigm(u2 + vrv * c + brv);
            float h = g2 * c + (1.0f - g2) * xv;
            hout[(size_t)t * D_IN + outc] = f2bf(h);
        }
    }
}

// ------------------------------ fc head ------------------------------------
// out[T][15] = h1[T][1024] @ fc_w[1024][15] + fc_b. One wave per 4 rows;
// lane covers k = lane*16 .. +16; shuffle-reduce over 64 lanes.
__global__ __launch_bounds__(256) void fc_kernel(const unsigned short* __restrict__ h,
                                                 const float* __restrict__ W,
                                                 const float* __restrict__ bias,
                                                 float* __restrict__ out) {
    int gwid = (int)((blockIdx.x * (size_t)blockDim.x + threadIdx.x) >> 6);
    int lane = threadIdx.x & 63;
    int r0 = gwid * 4;
    int k0 = lane * 16;

    float hv[4][16];
#pragma unroll
    for (int r = 0; r < 4; r++) {
#pragma unroll
        for (int i = 0; i < 16; i += 8) {
            short8v v = *(const short8v*)(h + (size_t)(r0 + r) * D_IN + k0 + i);
#pragma unroll
            for (int j = 0; j < 8; j++)
                hv[r][i + j] = bf2f((unsigned short)v[j]);
        }
    }
    float acc[4][NC];
#pragma unroll
    for (int r = 0; r < 4; r++)
#pragma unroll
        for (int cdx = 0; cdx < NC; cdx++) acc[r][cdx] = 0.0f;

#pragma unroll
    for (int i = 0; i < 16; i++) {
        const float* wrow = W + (size_t)(k0 + i) * NC;
#pragma unroll
        for (int cdx = 0; cdx < NC; cdx++) {
            float wv = wrow[cdx];
            acc[0][cdx] += hv[0][i] * wv;
            acc[1][cdx] += hv[1][i] * wv;
            acc[2][cdx] += hv[2][i] * wv;
            acc[3][cdx] += hv[3][i] * wv;
        }
    }
#pragma unroll
    for (int r = 0; r < 4; r++)
#pragma unroll
        for (int cdx = 0; cdx < NC; cdx++) {
            float s = acc[r][cdx];
#pragma unroll
            for (int m = 1; m < 64; m <<= 1) s += __shfl_xor(s, m, 64);
            acc[r][cdx] = s;
        }
#pragma unroll
    for (int r = 0; r < 4; r++) {
        float val = 0.0f;
#pragma unroll
        for (int cdx = 0; cdx < NC; cdx++)
            if (lane == cdx) val = acc[r][cdx];
        if (lane < NC) out[(size_t)(r0 + r) * NC + lane] = val + bias[lane];
    }
}

// ------------------------------ launcher -----------------------------------
extern "C" void kernel_launch(void* const* d_in, const int* in_sizes, int n_in,
                              void* d_out, int out_size, void* d_ws, size_t ws_size,
                              hipStream_t stream) {
    const float* x    = (const float*)d_in[0];
    const float* w0f  = (const float*)d_in[1];
    const float* v0f  = (const float*)d_in[2];
    const float* b0f  = (const float*)d_in[3];
    const float* w0b  = (const float*)d_in[4];
    const float* v0b  = (const float*)d_in[5];
    const float* b0b  = (const float*)d_in[6];
    const float* w1f  = (const float*)d_in[7];
    const float* v1f  = (const float*)d_in[8];
    const float* b1f  = (const float*)d_in[9];
    const float* w1b  = (const float*)d_in[10];
    const float* v1b  = (const float*)d_in[11];
    const float* b1b  = (const float*)d_in[12];
    const float* fcw  = (const float*)d_in[13];
    const float* fcb  = (const float*)d_in[14];
    float* out = (float*)d_out;

    char* ws = (char*)d_ws;
    const size_t XB_B = (size_t)T_LEN * D_IN * 2;   // 33.5 MB (also h1)
    const size_t WT_B = (size_t)NU * D_IN * 2;      // 3.15 MB each
    const size_t H0_B = (size_t)T_LEN * D_IN * 2;   // 33.5 MB
    const size_t U_B  = (size_t)T_LEN * NU * 2;     // 50.3 MB each (bf16)

    size_t off = 0;
    unsigned short* xb   = (unsigned short*)(ws + off); off += XB_B;
    unsigned short* h1   = xb;                            // alias: xb dead after layer-0 GEMMs
    unsigned short* wt0f = (unsigned short*)(ws + off); off += WT_B;
    unsigned short* wt0b = (unsigned short*)(ws + off); off += WT_B;
    unsigned short* wt1f = (unsigned short*)(ws + off); off += WT_B;
    unsigned short* wt1b = (unsigned short*)(ws + off); off += WT_B;
    unsigned short* h0   = (unsigned short*)(ws + off); off += H0_B;
    unsigned short* Uf   = (unsigned short*)(ws + off); off += U_B;
    unsigned short* Ub   = (unsigned short*)(ws + off); off += U_B;
    // total ~180 MB (same footprint as the round-2 f32 plan that fit)

    // 1. casts / transposes
    cast_f32_bf16<<<T_LEN * D_IN / 4 / 256, 256, 0, stream>>>(x, xb, (long)T_LEN * D_IN);
    dim3 tb(32, 8);
    dim3 tg(NU / 32, D_IN / 32);
    transpose_cast<<<tg, tb, 0, stream>>>(w0f, wt0f, D_IN, NU);
    transpose_cast<<<tg, tb, 0, stream>>>(w0b, wt0b, D_IN, NU);
    transpose_cast<<<tg, tb, 0, stream>>>(w1f, wt1f, D_IN, NU);
    transpose_cast<<<tg, tb, 0, stream>>>(w1b, wt1b, D_IN, NU);

    dim3 gg(T_LEN / BM, NU / BN);
    dim3 sg(HDIM / 64, NCHUNK, 2);

    // 2. layer 0
    gemm_bf16<unsigned short><<<gg, 256, 0, stream>>>(xb, wt0f, Uf, T_LEN, NU, D_IN);
    gemm_bf16<unsigned short><<<gg, 256, 0, stream>>>(xb, wt0b, Ub, T_LEN, NU, D_IN);
    sru_scan<float><<<sg, 64, 0, stream>>>(Uf, Ub, x, x + HDIM, v0f, b0f, v0b, b0b, h0);

    // 3. layer 1 (h1 aliases xb; xb no longer read)
    gemm_bf16<unsigned short><<<gg, 256, 0, stream>>>(h0, wt1f, Uf, T_LEN, NU, D_IN);
    gemm_bf16<unsigned short><<<gg, 256, 0, stream>>>(h0, wt1b, Ub, T_LEN, NU, D_IN);
    sru_scan<unsigned short><<<sg, 64, 0, stream>>>(Uf, Ub, h0, h0 + HDIM, v1f, b1f, v1b, b1b, h1);

    // 4. fc head
    fc_kernel<<<T_LEN / 4 * 64 / 256, 256, 0, stream>>>(h1, fcw, fcb, out);
    (void)in_sizes; (void)n_in; (void)out_size;
}

// Round 4
// 496.931 us; speedup vs baseline: 3.6248x; 1.0993x over previous
//
#include <hip/hip_runtime.h>

// ---------------------------------------------------------------------------
// SRU (2-layer bidirectional, v2 cell) + fc head for MI355X (gfx950).
//   1. cast x (f32 -> bf16)
//   2. transpose+cast 4 weight matrices W[K=1024][N=1536] -> Wt[N][K] bf16
//   3. per layer: GEMM Uf, GEMM Ub (bf16 out) ; one scan launch (both dirs)
//   4. fc head
// Scan: CHUNK=64, WARM=128 -> 4096 waves (16/CU). Rings hold RAW ushort bits
// (convert at consume, 8 steps later) so loads stay in flight depth-8.
// ---------------------------------------------------------------------------

#define T_LEN 16384
#define D_IN 1024
#define HDIM 512
#define NC 15
#define NU 1536          // 3*H columns in U
#define CHUNK 64
#define WARM 128
#define NCHUNK (T_LEN / CHUNK)   // 256

typedef __attribute__((ext_vector_type(8))) short short8v;
typedef __attribute__((ext_vector_type(4))) float float4v;
typedef __attribute__((ext_vector_type(4))) int int4v;

__device__ __forceinline__ unsigned short f2bf(float f) {
    unsigned u = __float_as_uint(f);
    unsigned r = (u + 0x7FFFu + ((u >> 16) & 1u)) >> 16;
    return (unsigned short)r;
}
__device__ __forceinline__ float bf2f(unsigned s) {
    return __uint_as_float(s << 16);
}
__device__ __forceinline__ void stc(float* p, float v) { *p = v; }
__device__ __forceinline__ void stc(unsigned short* p, float v) { *p = f2bf(v); }

__device__ __forceinline__ float sigm(float x) {
    float e = __expf(-x);
    return __builtin_amdgcn_rcpf(1.0f + e);
}

// -------------------------- cast x to bf16 ---------------------------------
__global__ __launch_bounds__(256) void cast_f32_bf16(const float* __restrict__ in,
                                                     unsigned short* __restrict__ out,
                                                     long n) {
    long i = ((long)blockIdx.x * blockDim.x + threadIdx.x) * 4;
    if (i + 3 < n) {
        float4v v = *(const float4v*)(in + i);
        unsigned short o0 = f2bf(v[0]), o1 = f2bf(v[1]), o2 = f2bf(v[2]), o3 = f2bf(v[3]);
        unsigned short* p = out + i;
        p[0] = o0; p[1] = o1; p[2] = o2; p[3] = o3;
    }
}

// ---------------- transpose + cast weights: [K][N] f32 -> [N][K] bf16 ------
__global__ __launch_bounds__(256) void transpose_cast(const float* __restrict__ w,
                                                      unsigned short* __restrict__ wt,
                                                      int K, int N) {
    __shared__ float tile[32][33];
    int n0 = blockIdx.x * 32, k0 = blockIdx.y * 32;
    int tx = threadIdx.x;   // 0..31
    int ty = threadIdx.y;   // 0..7
#pragma unroll
    for (int i = 0; i < 32; i += 8)
        tile[ty + i][tx] = w[(size_t)(k0 + ty + i) * N + n0 + tx];
    __syncthreads();
#pragma unroll
    for (int i = 0; i < 32; i += 8)
        wt[(size_t)(n0 + ty + i) * K + k0 + tx] = f2bf(tile[tx][ty + i]);
}

// ------------------------------ MFMA GEMM ----------------------------------
// C[M][N] = A[M][K] bf16 @ Wt[N][K] bf16 (i.e. W[K][N]), K = 1024.
// 128x128 tile, BK=64, 256 thr (4 waves, 2x2), each wave 64x64 = 4x4 frags.
// LDS XOR-swizzled (chunk ^= row&7) on both write and read -> conflict-free.
#define BM 128
#define BN 128
#define BK 64

template <typename CT>
__global__ __launch_bounds__(256) void gemm_bf16(const unsigned short* __restrict__ A,
                                                 const unsigned short* __restrict__ B,
                                                 CT* __restrict__ C,
                                                 int M, int N, int K) {
    __shared__ int4v lds[(BM * BK + BN * BK) * 2 / 16];
    char* ldsA = (char*)lds;
    char* ldsB = (char*)lds + BM * BK * 2;

    int tid = threadIdx.x;
    int m0 = blockIdx.x * BM;
    int n0 = blockIdx.y * BN;
    int wid = tid >> 6, lane = tid & 63;
    int wm = (wid >> 1) * 64, wn = (wid & 1) * 64;
    int l15 = lane & 15, l4 = lane >> 4;

    float4v acc[4][4] = {};

    for (int kt = 0; kt < K; kt += BK) {
        int4v av[4], bv[4];
#pragma unroll
        for (int i = 0; i < 4; i++) {
            int c = tid + i * 256;
            int row = c >> 3, cc = c & 7;
            av[i] = *(const int4v*)(A + (size_t)(m0 + row) * K + kt + cc * 8);
            bv[i] = *(const int4v*)(B + (size_t)(n0 + row) * K + kt + cc * 8);
        }
        __syncthreads();
#pragma unroll
        for (int i = 0; i < 4; i++) {
            int c = tid + i * 256;
            int row = c >> 3, cc = c & 7;
            int sw = (cc ^ (row & 7)) * 16;
            *(int4v*)(ldsA + row * 128 + sw) = av[i];
            *(int4v*)(ldsB + row * 128 + sw) = bv[i];
        }
        __syncthreads();
#pragma unroll
        for (int ks = 0; ks < 2; ks++) {
            short8v af[4], bfr[4];
#pragma unroll
            for (int f = 0; f < 4; f++) {
                int ra = wm + f * 16 + l15;
                int ca = ((ks * 4 + l4) ^ (ra & 7)) * 16;
                af[f] = *(const short8v*)(ldsA + ra * 128 + ca);
                int rb = wn + f * 16 + l15;
                int cb = ((ks * 4 + l4) ^ (rb & 7)) * 16;
                bfr[f] = *(const short8v*)(ldsB + rb * 128 + cb);
            }
#pragma unroll
            for (int fm = 0; fm < 4; fm++)
#pragma unroll
                for (int fn = 0; fn < 4; fn++)
                    acc[fm][fn] = __builtin_amdgcn_mfma_f32_16x16x32_bf16(
                        af[fm], bfr[fn], acc[fm][fn], 0, 0, 0);
        }
    }
    // epilogue: D[row=(l>>4)*4+j][col=l&15] per 16x16 frag (m89-verified layout)
#pragma unroll
    for (int fm = 0; fm < 4; fm++) {
        int r0 = m0 + wm + fm * 16 + l4 * 4;
#pragma unroll
        for (int fn = 0; fn < 4; fn++) {
            int c0 = n0 + wn + fn * 16 + l15;
#pragma unroll
            for (int j = 0; j < 4; j++)
                stc(&C[(size_t)(r0 + j) * N + c0], acc[fm][fn][j]);
        }
    }
}

// ------------------------------ SRU scan -----------------------------------
// Both directions in one launch (grid.z = 2). Block = (64 ch) x (4 chunks);
// each wave owns one (chunk, 64ch) pair -> 4096 independent waves (16/CU).
// Rings hold RAW loaded bits; bf16->f32 conversion happens at CONSUME time
// (8 steps after issue) so the compiler emits counted vmcnt and keeps
// depth-8 x 4 loads in flight. Warm-up WARM steps (u0,u1 only).
__global__ __launch_bounds__(256) void sru_scan(const unsigned short* __restrict__ Uf,
                                                const unsigned short* __restrict__ Ub,
                                                const unsigned short* __restrict__ xrf,
                                                const unsigned short* __restrict__ xrb,
                                                const float* __restrict__ vF,
                                                const float* __restrict__ bF,
                                                const float* __restrict__ vB,
                                                const float* __restrict__ bB,
                                                unsigned short* __restrict__ hout) {
    int dir = blockIdx.z;
    int ch = blockIdx.x * 64 + threadIdx.x;
    int cid = blockIdx.y * 4 + threadIdx.y;

    const unsigned short* U;
    const unsigned short* xr;
    const float* vv;
    const float* bb;
    int outc;
    if (dir == 0) { U = Uf; xr = xrf; vv = vF; bb = bF; outc = ch; }
    else          { U = Ub; xr = xrb; vv = vB; bb = bB; outc = HDIM + ch; }

    float vfv = vv[ch], vrv = vv[HDIM + ch];
    float bfv = bb[ch], brv = bb[HDIM + ch];

    int cb = cid * CHUNK;
    int mstart = dir ? cb + CHUNK - 1 : cb;   // first main-phase timestep
    int wstart, wn;                           // warm-up phase
    if (dir == 0) {
        wstart = cb - WARM; if (wstart < 0) wstart = 0;
        wn = cb - wstart;
    } else {
        wstart = cb + CHUNK - 1 + WARM; if (wstart > T_LEN - 1) wstart = T_LEN - 1;
        wn = wstart - (cb + CHUNK - 1);
    }

    constexpr int D = 8;
    // main-phase ring (RAW bits): issue FIRST -> hides under entire warm phase
    unsigned m0[D], m1[D], m2[D], mx[D];
#pragma unroll
    for (int d = 0; d < D; d++) {
        int t = dir ? mstart - d : mstart + d;
        size_t bi = (size_t)t * NU + ch;
        m0[d] = U[bi]; m1[d] = U[bi + HDIM]; m2[d] = U[bi + 2 * HDIM];
        mx[d] = xr[(size_t)t * D_IN + ch];
    }
    // warm-phase ring (u0,u1 only, RAW bits)
    unsigned w0[D], w1[D];
#pragma unroll
    for (int d = 0; d < D; d++) {
        if (d < wn) {
            int t = dir ? wstart - d : wstart + d;
            size_t bi = (size_t)t * NU + ch;
            w0[d] = U[bi]; w1[d] = U[bi + HDIM];
        }
    }

    float c = 0.0f;
    // warm-up: state only (wn is uniform across the wave)
    for (int nb = 0; nb < wn; nb += D) {
#pragma unroll
        for (int d = 0; d < D; d++) {
            int n = nb + d;
            if (n < wn) {
                float u0 = bf2f(w0[d]), u1 = bf2f(w1[d]);
                int np = n + D;
                if (np < wn) {
                    int tp = dir ? wstart - np : wstart + np;
                    size_t bi = (size_t)tp * NU + ch;
                    w0[d] = U[bi]; w1[d] = U[bi + HDIM];
                }
                float g1 = sigm(u1 + vfv * c + bfv);
                c = g1 * c + (1.0f - g1) * u0;
            }
        }
    }
    // main: full cell + h write (exactly CHUNK steps)
    for (int nb = 0; nb < CHUNK; nb += D) {
#pragma unroll
        for (int d = 0; d < D; d++) {
            int n = nb + d;
            int t = dir ? mstart - n : mstart + n;
            float u0 = bf2f(m0[d]), u1 = bf2f(m1[d]), u2 = bf2f(m2[d]), xv = bf2f(mx[d]);
            int np = n + D;
            if (np < CHUNK) {
                int tp = dir ? mstart - np : mstart + np;
                size_t bi = (size_t)tp * NU + ch;
                m0[d] = U[bi]; m1[d] = U[bi + HDIM]; m2[d] = U[bi + 2 * HDIM];
                mx[d] = xr[(size_t)tp * D_IN + ch];
            }
            float g1 = sigm(u1 + vfv * c + bfv);
            c = g1 * c + (1.0f - g1) * u0;
            float g2 = sigm(u2 + vrv * c + brv);
            float h = g2 * c + (1.0f - g2) * xv;
            hout[(size_t)t * D_IN + outc] = f2bf(h);
        }
    }
}

// ------------------------------ fc head ------------------------------------
// out[T][15] = h1[T][1024] @ fc_w[1024][15] + fc_b. One wave per 4 rows;
// lane covers k = lane*16 .. +16; shuffle-reduce over 64 lanes.
__global__ __launch_bounds__(256) void fc_kernel(const unsigned short* __restrict__ h,
                                                 const float* __restrict__ W,
                                                 const float* __restrict__ bias,
                                                 float* __restrict__ out) {
    int gwid = (int)((blockIdx.x * (size_t)blockDim.x + threadIdx.x) >> 6);
    int lane = threadIdx.x & 63;
    int r0 = gwid * 4;
    int k0 = lane * 16;

    float hv[4][16];
#pragma unroll
    for (int r = 0; r < 4; r++) {
#pragma unroll
        for (int i = 0; i < 16; i += 8) {
            short8v v = *(const short8v*)(h + (size_t)(r0 + r) * D_IN + k0 + i);
#pragma unroll
            for (int j = 0; j < 8; j++)
                hv[r][i + j] = bf2f((unsigned short)v[j]);
        }
    }
    float acc[4][NC];
#pragma unroll
    for (int r = 0; r < 4; r++)
#pragma unroll
        for (int cdx = 0; cdx < NC; cdx++) acc[r][cdx] = 0.0f;

#pragma unroll
    for (int i = 0; i < 16; i++) {
        const float* wrow = W + (size_t)(k0 + i) * NC;
#pragma unroll
        for (int cdx = 0; cdx < NC; cdx++) {
            float wv = wrow[cdx];
            acc[0][cdx] += hv[0][i] * wv;
            acc[1][cdx] += hv[1][i] * wv;
            acc[2][cdx] += hv[2][i] * wv;
            acc[3][cdx] += hv[3][i] * wv;
        }
    }
#pragma unroll
    for (int r = 0; r < 4; r++)
#pragma unroll
        for (int cdx = 0; cdx < NC; cdx++) {
            float s = acc[r][cdx];
#pragma unroll
            for (int m = 1; m < 64; m <<= 1) s += __shfl_xor(s, m, 64);
            acc[r][cdx] = s;
        }
#pragma unroll
    for (int r = 0; r < 4; r++) {
        float val = 0.0f;
#pragma unroll
        for (int cdx = 0; cdx < NC; cdx++)
            if (lane == cdx) val = acc[r][cdx];
        if (lane < NC) out[(size_t)(r0 + r) * NC + lane] = val + bias[lane];
    }
}

// ------------------------------ launcher -----------------------------------
extern "C" void kernel_launch(void* const* d_in, const int* in_sizes, int n_in,
                              void* d_out, int out_size, void* d_ws, size_t ws_size,
                              hipStream_t stream) {
    const float* x    = (const float*)d_in[0];
    const float* w0f  = (const float*)d_in[1];
    const float* v0f  = (const float*)d_in[2];
    const float* b0f  = (const float*)d_in[3];
    const float* w0b  = (const float*)d_in[4];
    const float* v0b  = (const float*)d_in[5];
    const float* b0b  = (const float*)d_in[6];
    const float* w1f  = (const float*)d_in[7];
    const float* v1f  = (const float*)d_in[8];
    const float* b1f  = (const float*)d_in[9];
    const float* w1b  = (const float*)d_in[10];
    const float* v1b  = (const float*)d_in[11];
    const float* b1b  = (const float*)d_in[12];
    const float* fcw  = (const float*)d_in[13];
    const float* fcb  = (const float*)d_in[14];
    float* out = (float*)d_out;

    char* ws = (char*)d_ws;
    const size_t XB_B = (size_t)T_LEN * D_IN * 2;   // 33.5 MB (also h1)
    const size_t WT_B = (size_t)NU * D_IN * 2;      // 3.15 MB each
    const size_t H0_B = (size_t)T_LEN * D_IN * 2;   // 33.5 MB
    const size_t U_B  = (size_t)T_LEN * NU * 2;     // 50.3 MB each (bf16)

    size_t off = 0;
    unsigned short* xb   = (unsigned short*)(ws + off); off += XB_B;
    unsigned short* h1   = xb;                            // alias: xb dead after layer-0 scan
    unsigned short* wt0f = (unsigned short*)(ws + off); off += WT_B;
    unsigned short* wt0b = (unsigned short*)(ws + off); off += WT_B;
    unsigned short* wt1f = (unsigned short*)(ws + off); off += WT_B;
    unsigned short* wt1b = (unsigned short*)(ws + off); off += WT_B;
    unsigned short* h0   = (unsigned short*)(ws + off); off += H0_B;
    unsigned short* Uf   = (unsigned short*)(ws + off); off += U_B;
    unsigned short* Ub   = (unsigned short*)(ws + off); off += U_B;
    // total ~180 MB (fits: same footprint as round-3 plan)

    // 1. casts / transposes
    cast_f32_bf16<<<T_LEN * D_IN / 4 / 256, 256, 0, stream>>>(x, xb, (long)T_LEN * D_IN);
    dim3 tb(32, 8);
    dim3 tg(NU / 32, D_IN / 32);
    transpose_cast<<<tg, tb, 0, stream>>>(w0f, wt0f, D_IN, NU);
    transpose_cast<<<tg, tb, 0, stream>>>(w0b, wt0b, D_IN, NU);
    transpose_cast<<<tg, tb, 0, stream>>>(w1f, wt1f, D_IN, NU);
    transpose_cast<<<tg, tb, 0, stream>>>(w1b, wt1b, D_IN, NU);

    dim3 gg(T_LEN / BM, NU / BN);
    dim3 sg(HDIM / 64, NCHUNK / 4, 2);
    dim3 sb(64, 4, 1);

    // 2. layer 0 (x_res read from xb, bf16)
    gemm_bf16<unsigned short><<<gg, 256, 0, stream>>>(xb, wt0f, Uf, T_LEN, NU, D_IN);
    gemm_bf16<unsigned short><<<gg, 256, 0, stream>>>(xb, wt0b, Ub, T_LEN, NU, D_IN);
    sru_scan<<<sg, sb, 0, stream>>>(Uf, Ub, xb, xb + HDIM, v0f, b0f, v0b, b0b, h0);

    // 3. layer 1 (h1 aliases xb; xb no longer read after layer-0 scan)
    gemm_bf16<unsigned short><<<gg, 256, 0, stream>>>(h0, wt1f, Uf, T_LEN, NU, D_IN);
    gemm_bf16<unsigned short><<<gg, 256, 0, stream>>>(h0, wt1b, Ub, T_LEN, NU, D_IN);
    sru_scan<<<sg, sb, 0, stream>>>(Uf, Ub, h0, h0 + HDIM, v1f, b1f, v1b, b1b, h1);

    // 4. fc head
    fc_kernel<<<T_LEN / 4 * 64 / 256, 256, 0, stream>>>(h1, fcw, fcb, out);
    (void)in_sizes; (void)n_in; (void)out_size;
}

// Round 5
// 473.640 us; speedup vs baseline: 3.8030x; 1.0492x over previous
//
#include <hip/hip_runtime.h>

// ---------------------------------------------------------------------------
// SRU (2-layer bidirectional, v2 cell) + fc head for MI355X (gfx950).
//   1. cast x (f32 -> bf16)
//   2. transpose+cast 4 weight matrices W[K=1024][N=1536] -> Wt[N][K] bf16
//   3. per layer: 2x GEMM writing PACKED U (P01 = u0|u1', P2 = u2', with
//      bias and -log2e prescale folded in) ; one scan launch (both dirs)
//   4. fc head
// Scan: CHUNK=64, WARM=64 -> 4096 waves. Warm ring issued first (in-order
// vmcnt), depth-16 raw-bit rings, sigmoid = rcp(1+exp2(fma)).
// ---------------------------------------------------------------------------

#define T_LEN 16384
#define D_IN 1024
#define HDIM 512
#define NC 15
#define NU 1536          // 3*H columns in U
#define CHUNK 64
#define WARM 64
#define NCHUNK (T_LEN / CHUNK)   // 256
#define L2E 1.44269504f

typedef __attribute__((ext_vector_type(8))) short short8v;
typedef __attribute__((ext_vector_type(4))) float float4v;
typedef __attribute__((ext_vector_type(4))) int int4v;

__device__ __forceinline__ unsigned short f2bf(float f) {
    unsigned u = __float_as_uint(f);
    unsigned r = (u + 0x7FFFu + ((u >> 16) & 1u)) >> 16;
    return (unsigned short)r;
}
__device__ __forceinline__ float bf2f(unsigned s) {
    return __uint_as_float(s << 16);
}
__device__ __forceinline__ float sigm2(float zarg) {   // 1/(1+2^zarg)
    float e = __builtin_amdgcn_exp2f(zarg);
    return __builtin_amdgcn_rcpf(1.0f + e);
}

// -------------------------- cast x to bf16 ---------------------------------
__global__ __launch_bounds__(256) void cast_f32_bf16(const float* __restrict__ in,
                                                     unsigned short* __restrict__ out,
                                                     long n) {
    long i = ((long)blockIdx.x * blockDim.x + threadIdx.x) * 4;
    if (i + 3 < n) {
        float4v v = *(const float4v*)(in + i);
        unsigned short o0 = f2bf(v[0]), o1 = f2bf(v[1]), o2 = f2bf(v[2]), o3 = f2bf(v[3]);
        unsigned short* p = out + i;
        p[0] = o0; p[1] = o1; p[2] = o2; p[3] = o3;
    }
}

// ---------------- transpose + cast weights: [K][N] f32 -> [N][K] bf16 ------
__global__ __launch_bounds__(256) void transpose_cast(const float* __restrict__ w,
                                                      unsigned short* __restrict__ wt,
                                                      int K, int N) {
    __shared__ float tile[32][33];
    int n0 = blockIdx.x * 32, k0 = blockIdx.y * 32;
    int tx = threadIdx.x;   // 0..31
    int ty = threadIdx.y;   // 0..7
#pragma unroll
    for (int i = 0; i < 32; i += 8)
        tile[ty + i][tx] = w[(size_t)(k0 + ty + i) * N + n0 + tx];
    __syncthreads();
#pragma unroll
    for (int i = 0; i < 32; i += 8)
        wt[(size_t)(n0 + ty + i) * K + k0 + tx] = f2bf(tile[tx][ty + i]);
}

// ------------------------------ MFMA GEMM ----------------------------------
// U[M][1536] = A[M][K] bf16 @ Wt[N][K] bf16, K = 1024, then packed-stored:
//   col c < 512   (u0):  P01[(t*512+ch)*2]     = bf16(val)
//   512..1023     (u1):  P01[(t*512+ch)*2 + 1] = bf16(-L2E*(val + bf[ch]))
//   1024..1535    (u2):  P2[t*512+ch]          = bf16(-L2E*(val + br[ch]))
// 128x128 tile, BK=64, 4 waves (2x2), LDS XOR-swizzled, conflict-free.
#define BM 128
#define BN 128
#define BK 64

__global__ __launch_bounds__(256) void gemm_pack(const unsigned short* __restrict__ A,
                                                 const unsigned short* __restrict__ B,
                                                 unsigned short* __restrict__ P01,
                                                 unsigned short* __restrict__ P2,
                                                 const float* __restrict__ bias,
                                                 int M, int N, int K) {
    __shared__ int4v lds[(BM * BK + BN * BK) * 2 / 16];
    char* ldsA = (char*)lds;
    char* ldsB = (char*)lds + BM * BK * 2;

    int tid = threadIdx.x;
    int m0 = blockIdx.x * BM;
    int n0 = blockIdx.y * BN;
    int wid = tid >> 6, lane = tid & 63;
    int wm = (wid >> 1) * 64, wn = (wid & 1) * 64;
    int l15 = lane & 15, l4 = lane >> 4;

    float4v acc[4][4] = {};

    for (int kt = 0; kt < K; kt += BK) {
        int4v av[4], bv[4];
#pragma unroll
        for (int i = 0; i < 4; i++) {
            int c = tid + i * 256;
            int row = c >> 3, cc = c & 7;
            av[i] = *(const int4v*)(A + (size_t)(m0 + row) * K + kt + cc * 8);
            bv[i] = *(const int4v*)(B + (size_t)(n0 + row) * K + kt + cc * 8);
        }
        __syncthreads();
#pragma unroll
        for (int i = 0; i < 4; i++) {
            int c = tid + i * 256;
            int row = c >> 3, cc = c & 7;
            int sw = (cc ^ (row & 7)) * 16;
            *(int4v*)(ldsA + row * 128 + sw) = av[i];
            *(int4v*)(ldsB + row * 128 + sw) = bv[i];
        }
        __syncthreads();
#pragma unroll
        for (int ks = 0; ks < 2; ks++) {
            short8v af[4], bfr[4];
#pragma unroll
            for (int f = 0; f < 4; f++) {
                int ra = wm + f * 16 + l15;
                int ca = ((ks * 4 + l4) ^ (ra & 7)) * 16;
                af[f] = *(const short8v*)(ldsA + ra * 128 + ca);
                int rb = wn + f * 16 + l15;
                int cb = ((ks * 4 + l4) ^ (rb & 7)) * 16;
                bfr[f] = *(const short8v*)(ldsB + rb * 128 + cb);
            }
#pragma unroll
            for (int fm = 0; fm < 4; fm++)
#pragma unroll
                for (int fn = 0; fn < 4; fn++)
                    acc[fm][fn] = __builtin_amdgcn_mfma_f32_16x16x32_bf16(
                        af[fm], bfr[fn], acc[fm][fn], 0, 0, 0);
        }
    }
    // epilogue: D[row=(l>>4)*4+j][col=l&15]; packed-store per 512-col group.
#pragma unroll
    for (int fm = 0; fm < 4; fm++) {
        int r0 = m0 + wm + fm * 16 + l4 * 4;
#pragma unroll
        for (int fn = 0; fn < 4; fn++) {
            int cbase = n0 + wn + fn * 16;           // 16-aligned -> jj lane-uniform
            int jj = cbase >> 9;
            int ch = (cbase & 511) + l15;
#pragma unroll
            for (int j = 0; j < 4; j++) {
                unsigned t = (unsigned)(r0 + j);
                float val = acc[fm][fn][j];
                if (jj == 0) {
                    P01[(t * 512u + ch) * 2u] = f2bf(val);
                } else if (jj == 1) {
                    P01[(t * 512u + ch) * 2u + 1u] = f2bf(-L2E * (val + bias[ch]));
                } else {
                    P2[t * 512u + ch] = f2bf(-L2E * (val + bias[HDIM + ch]));
                }
            }
        }
    }
}

// ------------------------------ SRU scan -----------------------------------
// Both directions in one launch (grid.z = 2). Block = (64 ch) x (4 chunks);
// 4096 independent waves. Rings hold RAW bits, convert at consume (16 steps
// later). Warm ring issued FIRST (vmcnt completes in issue order), then main
// ring hides under the whole warm phase. Warm = 1 dword load/step.
#define DPF 16
__global__ __launch_bounds__(256, 4) void sru_scan(
        const unsigned* __restrict__ P01f, const unsigned short* __restrict__ P2f,
        const unsigned* __restrict__ P01b, const unsigned short* __restrict__ P2b,
        const unsigned short* __restrict__ xrf, const unsigned short* __restrict__ xrb,
        const float* __restrict__ vF, const float* __restrict__ vB,
        unsigned short* __restrict__ hout) {
    int dir = blockIdx.z;
    int ch = blockIdx.x * 64 + threadIdx.x;
    int cid = blockIdx.y * 4 + threadIdx.y;

    const unsigned* P01;
    const unsigned short* P2;
    const unsigned short* xr;
    const float* vv;
    int outc;
    if (dir == 0) { P01 = P01f; P2 = P2f; xr = xrf; vv = vF; outc = ch; }
    else          { P01 = P01b; P2 = P2b; xr = xrb; vv = vB; outc = HDIM + ch; }

    float vfs = -L2E * vv[ch];
    float vrs = -L2E * vv[HDIM + ch];

    int cb = cid * CHUNK;
    int tstep = dir ? -1 : 1;
    int mstart = dir ? cb + CHUNK - 1 : cb;
    int wstart, wn;
    if (dir == 0) {
        wstart = cb - WARM; if (wstart < 0) wstart = 0;
        wn = cb - wstart;
    } else {
        wstart = cb + CHUNK - 1 + WARM; if (wstart > T_LEN - 1) wstart = T_LEN - 1;
        wn = wstart - (cb + CHUNK - 1);
    }

    // warm ring FIRST (oldest loads complete first)
    unsigned wr_[DPF];
#pragma unroll
    for (int d = 0; d < DPF; d++) {
        if (d < wn) {
            int t = wstart + tstep * d;
            wr_[d] = P01[(unsigned)t * 512u + ch];
        }
    }
    // main ring (hides under warm phase)
    unsigned a01[DPF], a2[DPF], ax[DPF];
#pragma unroll
    for (int d = 0; d < DPF; d++) {
        int t = mstart + tstep * d;
        unsigned bi = (unsigned)t * 512u + ch;
        a01[d] = P01[bi]; a2[d] = P2[bi];
        ax[d] = xr[(unsigned)t * 1024u + ch];
    }

    float c = 0.0f;
    // warm-up: state only (wn uniform across the wave)
    for (int nb = 0; nb < wn; nb += DPF) {
#pragma unroll
        for (int d = 0; d < DPF; d++) {
            int n = nb + d;
            if (n < wn) {
                unsigned w = wr_[d];
                float u0 = bf2f(w << 16 >> 16);   // lo half
                float u1s = __uint_as_float(w & 0xffff0000u);
                int np = n + DPF;
                if (np < wn) {
                    int tp = wstart + tstep * np;
                    wr_[d] = P01[(unsigned)tp * 512u + ch];
                }
                float g1 = sigm2(fmaf(vfs, c, u1s));
                c = u0 + g1 * (c - u0);
            }
        }
    }
    // main: full cell + h write (exactly CHUNK steps)
    for (int nb = 0; nb < CHUNK; nb += DPF) {
#pragma unroll
        for (int d = 0; d < DPF; d++) {
            int n = nb + d;
            int t = mstart + tstep * n;
            unsigned p = a01[d];
            float u0 = bf2f(p << 16 >> 16);
            float u1s = __uint_as_float(p & 0xffff0000u);
            float u2s = bf2f(a2[d]);
            float xv = bf2f(ax[d]);
            int np = n + DPF;
            if (np < CHUNK) {
                int tp = mstart + tstep * np;
                unsigned bi = (unsigned)tp * 512u + ch;
                a01[d] = P01[bi]; a2[d] = P2[bi];
                ax[d] = xr[(unsigned)tp * 1024u + ch];
            }
            float g1 = sigm2(fmaf(vfs, c, u1s));
            c = u0 + g1 * (c - u0);
            float g2 = sigm2(fmaf(vrs, c, u2s));
            float h = xv + g2 * (c - xv);
            hout[(unsigned)t * 1024u + outc] = f2bf(h);
        }
    }
}

// ------------------------------ fc head ------------------------------------
// out[T][15] = h1[T][1024] @ fc_w[1024][15] + fc_b. One wave per 4 rows.
__global__ __launch_bounds__(256) void fc_kernel(const unsigned short* __restrict__ h,
                                                 const float* __restrict__ W,
                                                 const float* __restrict__ bias,
                                                 float* __restrict__ out) {
    int gwid = (int)((blockIdx.x * (size_t)blockDim.x + threadIdx.x) >> 6);
    int lane = threadIdx.x & 63;
    int r0 = gwid * 4;
    int k0 = lane * 16;

    float hv[4][16];
#pragma unroll
    for (int r = 0; r < 4; r++) {
#pragma unroll
        for (int i = 0; i < 16; i += 8) {
            short8v v = *(const short8v*)(h + (size_t)(r0 + r) * D_IN + k0 + i);
#pragma unroll
            for (int j = 0; j < 8; j++)
                hv[r][i + j] = bf2f((unsigned short)v[j]);
        }
    }
    float acc[4][NC];
#pragma unroll
    for (int r = 0; r < 4; r++)
#pragma unroll
        for (int cdx = 0; cdx < NC; cdx++) acc[r][cdx] = 0.0f;

#pragma unroll
    for (int i = 0; i < 16; i++) {
        const float* wrow = W + (size_t)(k0 + i) * NC;
#pragma unroll
        for (int cdx = 0; cdx < NC; cdx++) {
            float wv = wrow[cdx];
            acc[0][cdx] += hv[0][i] * wv;
            acc[1][cdx] += hv[1][i] * wv;
            acc[2][cdx] += hv[2][i] * wv;
            acc[3][cdx] += hv[3][i] * wv;
        }
    }
#pragma unroll
    for (int r = 0; r < 4; r++)
#pragma unroll
        for (int cdx = 0; cdx < NC; cdx++) {
            float s = acc[r][cdx];
#pragma unroll
            for (int m = 1; m < 64; m <<= 1) s += __shfl_xor(s, m, 64);
            acc[r][cdx] = s;
        }
#pragma unroll
    for (int r = 0; r < 4; r++) {
        float val = 0.0f;
#pragma unroll
        for (int cdx = 0; cdx < NC; cdx++)
            if (lane == cdx) val = acc[r][cdx];
        if (lane < NC) out[(size_t)(r0 + r) * NC + lane] = val + bias[lane];
    }
}

// ------------------------------ launcher -----------------------------------
extern "C" void kernel_launch(void* const* d_in, const int* in_sizes, int n_in,
                              void* d_out, int out_size, void* d_ws, size_t ws_size,
                              hipStream_t stream) {
    const float* x    = (const float*)d_in[0];
    const float* w0f  = (const float*)d_in[1];
    const float* v0f  = (const float*)d_in[2];
    const float* b0f  = (const float*)d_in[3];
    const float* w0b  = (const float*)d_in[4];
    const float* v0b  = (const float*)d_in[5];
    const float* b0b  = (const float*)d_in[6];
    const float* w1f  = (const float*)d_in[7];
    const float* v1f  = (const float*)d_in[8];
    const float* b1f  = (const float*)d_in[9];
    const float* w1b  = (const float*)d_in[10];
    const float* v1b  = (const float*)d_in[11];
    const float* b1b  = (const float*)d_in[12];
    const float* fcw  = (const float*)d_in[13];
    const float* fcb  = (const float*)d_in[14];
    float* out = (float*)d_out;

    char* ws = (char*)d_ws;
    const size_t XB_B  = (size_t)T_LEN * D_IN * 2;   // 33.5 MB (also h1)
    const size_t WT_B  = (size_t)NU * D_IN * 2;      // 3.15 MB each
    const size_t H0_B  = (size_t)T_LEN * D_IN * 2;   // 33.5 MB
    const size_t P01_B = (size_t)T_LEN * HDIM * 4;   // 33.5 MB each dir
    const size_t P2_B  = (size_t)T_LEN * HDIM * 2;   // 16.8 MB each dir

    size_t off = 0;
    unsigned short* xb   = (unsigned short*)(ws + off); off += XB_B;
    unsigned short* h1   = xb;                            // alias: xb dead after layer-0 GEMMs
    unsigned short* wt0f = (unsigned short*)(ws + off); off += WT_B;
    unsigned short* wt0b = (unsigned short*)(ws + off); off += WT_B;
    unsigned short* wt1f = (unsigned short*)(ws + off); off += WT_B;
    unsigned short* wt1b = (unsigned short*)(ws + off); off += WT_B;
    unsigned short* h0   = (unsigned short*)(ws + off); off += H0_B;
    unsigned short* P01F = (unsigned short*)(ws + off); off += P01_B;
    unsigned short* P2F  = (unsigned short*)(ws + off); off += P2_B;
    unsigned short* P01B = (unsigned short*)(ws + off); off += P01_B;
    unsigned short* P2B  = (unsigned short*)(ws + off); off += P2_B;
    // total 180.3 MB — identical footprint to the round-3/4 plan that fit.

    // 1. casts / transposes
    cast_f32_bf16<<<T_LEN * D_IN / 4 / 256, 256, 0, stream>>>(x, xb, (long)T_LEN * D_IN);
    dim3 tb(32, 8);
    dim3 tg(NU / 32, D_IN / 32);
    transpose_cast<<<tg, tb, 0, stream>>>(w0f, wt0f, D_IN, NU);
    transpose_cast<<<tg, tb, 0, stream>>>(w0b, wt0b, D_IN, NU);
    transpose_cast<<<tg, tb, 0, stream>>>(w1f, wt1f, D_IN, NU);
    transpose_cast<<<tg, tb, 0, stream>>>(w1b, wt1b, D_IN, NU);

    dim3 gg(T_LEN / BM, NU / BN);
    dim3 sg(HDIM / 64, NCHUNK / 4, 2);
    dim3 sb(64, 4, 1);

    // 2. layer 0 (x_res read from xb, bf16)
    gemm_pack<<<gg, 256, 0, stream>>>(xb, wt0f, P01F, P2F, b0f, T_LEN, NU, D_IN);
    gemm_pack<<<gg, 256, 0, stream>>>(xb, wt0b, P01B, P2B, b0b, T_LEN, NU, D_IN);
    sru_scan<<<sg, sb, 0, stream>>>((const unsigned*)P01F, P2F, (const unsigned*)P01B, P2B,
                                    xb, xb + HDIM, v0f, v0b, h0);

    // 3. layer 1 (h1 aliases xb; xb no longer read after layer-0 scan)
    gemm_pack<<<gg, 256, 0, stream>>>(h0, wt1f, P01F, P2F, b1f, T_LEN, NU, D_IN);
    gemm_pack<<<gg, 256, 0, stream>>>(h0, wt1b, P01B, P2B, b1b, T_LEN, NU, D_IN);
    sru_scan<<<sg, sb, 0, stream>>>((const unsigned*)P01F, P2F, (const unsigned*)P01B, P2B,
                                    h0, h0 + HDIM, v1f, v1b, h1);

    // 4. fc head
    fc_kernel<<<T_LEN / 4 * 64 / 256, 256, 0, stream>>>(h1, fcw, fcb, out);
    (void)in_sizes; (void)n_in; (void)out_size;
}

// Round 6
// 464.814 us; speedup vs baseline: 3.8752x; 1.0190x over previous
//
#include <hip/hip_runtime.h>

// ---------------------------------------------------------------------------
// SRU (2-layer bidirectional, v2 cell) + fc head for MI355X (gfx950).
//   1. cast x (f32 -> bf16)
//   2. transpose+cast weights into ONE concatenated Wt[3072][1024] per layer
//   3. per layer: ONE fused GEMM (N=3072) writing 6 separate planes
//      (U0,U1',U2' per dir; U1'/U2' have bias and -log2e folded in),
//      coalesced unit-stride bf16 stores; then one scan launch (both dirs)
//   4. fc head
// Scan: CHUNK=64, WARM=64, raw-bit rings (convert at consume), warm ring
// issued first, depth 16 main / 8 warm.
// ---------------------------------------------------------------------------

#define T_LEN 16384
#define D_IN 1024
#define HDIM 512
#define NC 15
#define NU2 3072         // both directions' 3*H columns
#define CHUNK 64
#define WARM 64
#define NCHUNK (T_LEN / CHUNK)   // 256
#define L2E 1.44269504f

typedef __attribute__((ext_vector_type(8))) short short8v;
typedef __attribute__((ext_vector_type(4))) float float4v;
typedef __attribute__((ext_vector_type(4))) int int4v;

__device__ __forceinline__ unsigned short f2bf(float f) {
    unsigned u = __float_as_uint(f);
    unsigned r = (u + 0x7FFFu + ((u >> 16) & 1u)) >> 16;
    return (unsigned short)r;
}
__device__ __forceinline__ float bf2f(unsigned s) {
    return __uint_as_float(s << 16);
}
__device__ __forceinline__ float sigm2(float zarg) {   // 1/(1+2^zarg)
    float e = __builtin_amdgcn_exp2f(zarg);
    return __builtin_amdgcn_rcpf(1.0f + e);
}

// -------------------------- cast x to bf16 ---------------------------------
__global__ __launch_bounds__(256) void cast_f32_bf16(const float* __restrict__ in,
                                                     unsigned short* __restrict__ out,
                                                     long n) {
    long i = ((long)blockIdx.x * blockDim.x + threadIdx.x) * 4;
    if (i + 3 < n) {
        float4v v = *(const float4v*)(in + i);
        unsigned short o0 = f2bf(v[0]), o1 = f2bf(v[1]), o2 = f2bf(v[2]), o3 = f2bf(v[3]);
        unsigned short* p = out + i;
        p[0] = o0; p[1] = o1; p[2] = o2; p[3] = o3;
    }
}

// ---------------- transpose + cast weights: [K][N] f32 -> [N][K] bf16 ------
__global__ __launch_bounds__(256) void transpose_cast(const float* __restrict__ w,
                                                      unsigned short* __restrict__ wt,
                                                      int K, int N) {
    __shared__ float tile[32][33];
    int n0 = blockIdx.x * 32, k0 = blockIdx.y * 32;
    int tx = threadIdx.x;   // 0..31
    int ty = threadIdx.y;   // 0..7
#pragma unroll
    for (int i = 0; i < 32; i += 8)
        tile[ty + i][tx] = w[(size_t)(k0 + ty + i) * N + n0 + tx];
    __syncthreads();
#pragma unroll
    for (int i = 0; i < 32; i += 8)
        wt[(size_t)(n0 + ty + i) * K + k0 + tx] = f2bf(tile[tx][ty + i]);
}

// ------------------------------ fused MFMA GEMM ----------------------------
// U[M][3072] = A[M][K] bf16 @ Wt[3072][K] bf16, K = 1024, stored into 6
// planes of [T][512] bf16 (plane = n0>>9, uniform per block):
//   0: u0_f          1: -L2E*(u1_f + bf_f)   2: -L2E*(u2_f + br_f)
//   3: u0_b          4: -L2E*(u1_b + bf_b)   5: -L2E*(u2_b + br_b)
// 128x128 tile, BK=64, 4 waves (2x2), LDS XOR-swizzled, conflict-free.
// grid.x = N-tiles (24) fastest -> consecutive blocks reuse the A-tile in L2.
#define BM 128
#define BN 128
#define BK 64

__global__ __launch_bounds__(256) void gemm_fused(const unsigned short* __restrict__ A,
                                                  const unsigned short* __restrict__ Bt,
                                                  unsigned short* __restrict__ P0F,
                                                  unsigned short* __restrict__ P1F,
                                                  unsigned short* __restrict__ P2F,
                                                  unsigned short* __restrict__ P0B,
                                                  unsigned short* __restrict__ P1B,
                                                  unsigned short* __restrict__ P2B,
                                                  const float* __restrict__ bias_f,
                                                  const float* __restrict__ bias_b,
                                                  int M, int K) {
    __shared__ int4v lds[(BM * BK + BN * BK) * 2 / 16];
    char* ldsA = (char*)lds;
    char* ldsB = (char*)lds + BM * BK * 2;

    int tid = threadIdx.x;
    int n0 = blockIdx.x * BN;    // N fastest -> A-tile L2 reuse
    int m0 = blockIdx.y * BM;
    int wid = tid >> 6, lane = tid & 63;
    int wm = (wid >> 1) * 64, wn = (wid & 1) * 64;
    int l15 = lane & 15, l4 = lane >> 4;

    float4v acc[4][4] = {};

    for (int kt = 0; kt < K; kt += BK) {
        int4v av[4], bv[4];
#pragma unroll
        for (int i = 0; i < 4; i++) {
            int c = tid + i * 256;
            int row = c >> 3, cc = c & 7;
            av[i] = *(const int4v*)(A + (size_t)(m0 + row) * K + kt + cc * 8);
            bv[i] = *(const int4v*)(Bt + (size_t)(n0 + row) * K + kt + cc * 8);
        }
        __syncthreads();
#pragma unroll
        for (int i = 0; i < 4; i++) {
            int c = tid + i * 256;
            int row = c >> 3, cc = c & 7;
            int sw = (cc ^ (row & 7)) * 16;
            *(int4v*)(ldsA + row * 128 + sw) = av[i];
            *(int4v*)(ldsB + row * 128 + sw) = bv[i];
        }
        __syncthreads();
#pragma unroll
        for (int ks = 0; ks < 2; ks++) {
            short8v af[4], bfr[4];
#pragma unroll
            for (int f = 0; f < 4; f++) {
                int ra = wm + f * 16 + l15;
                int ca = ((ks * 4 + l4) ^ (ra & 7)) * 16;
                af[f] = *(const short8v*)(ldsA + ra * 128 + ca);
                int rb = wn + f * 16 + l15;
                int cb = ((ks * 4 + l4) ^ (rb & 7)) * 16;
                bfr[f] = *(const short8v*)(ldsB + rb * 128 + cb);
            }
#pragma unroll
            for (int fm = 0; fm < 4; fm++)
#pragma unroll
                for (int fn = 0; fn < 4; fn++)
                    acc[fm][fn] = __builtin_amdgcn_mfma_f32_16x16x32_bf16(
                        af[fm], bfr[fn], acc[fm][fn], 0, 0, 0);
        }
    }

    // ---- epilogue: plane select (uniform per block), branch-free fma+store
    int plane = n0 >> 9;   // 0..5
    unsigned short* dst;
    const float* bp;
    if      (plane == 0) { dst = P0F; bp = nullptr; }
    else if (plane == 1) { dst = P1F; bp = bias_f; }
    else if (plane == 2) { dst = P2F; bp = bias_f + HDIM; }
    else if (plane == 3) { dst = P0B; bp = nullptr; }
    else if (plane == 4) { dst = P1B; bp = bias_b; }
    else                 { dst = P2B; bp = bias_b + HDIM; }
    float smul = bp ? -L2E : 1.0f;
    int cip0 = (n0 & 511) + wn;   // col-in-plane base for this wave

    float tadd[4];
#pragma unroll
    for (int fn = 0; fn < 4; fn++)
        tadd[fn] = bp ? -L2E * bp[cip0 + fn * 16 + l15] : 0.0f;

    // D[row=(l>>4)*4+j][col=l&15] per 16x16 frag (m89-verified layout)
#pragma unroll
    for (int fm = 0; fm < 4; fm++) {
        int r0 = m0 + wm + fm * 16 + l4 * 4;
#pragma unroll
        for (int fn = 0; fn < 4; fn++) {
            int chp = cip0 + fn * 16 + l15;
#pragma unroll
            for (int j = 0; j < 4; j++)
                dst[(size_t)(r0 + j) * 512 + chp] =
                    f2bf(fmaf(smul, acc[fm][fn][j], tadd[fn]));
        }
    }
}

// ------------------------------ SRU scan -----------------------------------
// Both directions in one launch (grid.z = 2). Block = (64 ch) x (4 chunks);
// 4096 independent waves. Raw-bit rings, convert at consume. Warm ring
// issued FIRST (vmcnt completes in issue order). Warm = 2 loads/step,
// main = 4 loads/step.
#define DM 16
#define DW 8
__global__ __launch_bounds__(256, 4) void sru_scan(
        const unsigned short* __restrict__ P0f, const unsigned short* __restrict__ P1f,
        const unsigned short* __restrict__ P2f,
        const unsigned short* __restrict__ P0b, const unsigned short* __restrict__ P1b,
        const unsigned short* __restrict__ P2b,
        const unsigned short* __restrict__ xrf, const unsigned short* __restrict__ xrb,
        const float* __restrict__ vF, const float* __restrict__ vB,
        unsigned short* __restrict__ hout) {
    int dir = blockIdx.z;
    int ch = blockIdx.x * 64 + threadIdx.x;
    int cid = blockIdx.y * 4 + threadIdx.y;

    const unsigned short *P0, *P1, *P2, *xr;
    const float* vv;
    int outc;
    if (dir == 0) { P0 = P0f; P1 = P1f; P2 = P2f; xr = xrf; vv = vF; outc = ch; }
    else          { P0 = P0b; P1 = P1b; P2 = P2b; xr = xrb; vv = vB; outc = HDIM + ch; }

    float vfs = -L2E * vv[ch];
    float vrs = -L2E * vv[HDIM + ch];

    int cb = cid * CHUNK;
    int tstep = dir ? -1 : 1;
    int mstart = dir ? cb + CHUNK - 1 : cb;
    int wstart, wn;
    if (dir == 0) {
        wstart = cb - WARM; if (wstart < 0) wstart = 0;
        wn = cb - wstart;
    } else {
        wstart = cb + CHUNK - 1 + WARM; if (wstart > T_LEN - 1) wstart = T_LEN - 1;
        wn = wstart - (cb + CHUNK - 1);
    }

    // warm rings FIRST (oldest loads complete first)
    unsigned w0r[DW], w1r[DW];
#pragma unroll
    for (int d = 0; d < DW; d++) {
        if (d < wn) {
            int t = wstart + tstep * d;
            unsigned bi = (unsigned)t * 512u + ch;
            w0r[d] = P0[bi]; w1r[d] = P1[bi];
        }
    }
    // main rings (hide under whole warm phase)
    unsigned a0[DM], a1[DM], a2[DM], axr[DM];
#pragma unroll
    for (int d = 0; d < DM; d++) {
        int t = mstart + tstep * d;
        unsigned bi = (unsigned)t * 512u + ch;
        a0[d] = P0[bi]; a1[d] = P1[bi]; a2[d] = P2[bi];
        axr[d] = xr[(unsigned)t * 1024u + ch];
    }

    float c = 0.0f;
    // warm-up: state only (wn uniform across the wave)
    for (int nb = 0; nb < wn; nb += DW) {
#pragma unroll
        for (int d = 0; d < DW; d++) {
            int n = nb + d;
            if (n < wn) {
                float u0 = bf2f(w0r[d]);
                float u1s = bf2f(w1r[d]);
                int np = n + DW;
                if (np < wn) {
                    int tp = wstart + tstep * np;
                    unsigned bi = (unsigned)tp * 512u + ch;
                    w0r[d] = P0[bi]; w1r[d] = P1[bi];
                }
                float g1 = sigm2(fmaf(vfs, c, u1s));
                c = u0 + g1 * (c - u0);
            }
        }
    }
    // main: full cell + h write (exactly CHUNK steps, CHUNK % DM == 0)
    for (int nb = 0; nb < CHUNK; nb += DM) {
#pragma unroll
        for (int d = 0; d < DM; d++) {
            int n = nb + d;
            int t = mstart + tstep * n;
            float u0 = bf2f(a0[d]);
            float u1s = bf2f(a1[d]);
            float u2s = bf2f(a2[d]);
            float xv = bf2f(axr[d]);
            int np = n + DM;
            if (np < CHUNK) {
                int tp = mstart + tstep * np;
                unsigned bi = (unsigned)tp * 512u + ch;
                a0[d] = P0[bi]; a1[d] = P1[bi]; a2[d] = P2[bi];
                axr[d] = xr[(unsigned)tp * 1024u + ch];
            }
            float g1 = sigm2(fmaf(vfs, c, u1s));
            c = u0 + g1 * (c - u0);
            float g2 = sigm2(fmaf(vrs, c, u2s));
            float h = xv + g2 * (c - xv);
            hout[(unsigned)t * 1024u + outc] = f2bf(h);
        }
    }
}

// ------------------------------ fc head ------------------------------------
// out[T][15] = h1[T][1024] @ fc_w[1024][15] + fc_b. One wave per 4 rows.
__global__ __launch_bounds__(256) void fc_kernel(const unsigned short* __restrict__ h,
                                                 const float* __restrict__ W,
                                                 const float* __restrict__ bias,
                                                 float* __restrict__ out) {
    int gwid = (int)((blockIdx.x * (size_t)blockDim.x + threadIdx.x) >> 6);
    int lane = threadIdx.x & 63;
    int r0 = gwid * 4;
    int k0 = lane * 16;

    float hv[4][16];
#pragma unroll
    for (int r = 0; r < 4; r++) {
#pragma unroll
        for (int i = 0; i < 16; i += 8) {
            short8v v = *(const short8v*)(h + (size_t)(r0 + r) * D_IN + k0 + i);
#pragma unroll
            for (int j = 0; j < 8; j++)
                hv[r][i + j] = bf2f((unsigned short)v[j]);
        }
    }
    float acc[4][NC];
#pragma unroll
    for (int r = 0; r < 4; r++)
#pragma unroll
        for (int cdx = 0; cdx < NC; cdx++) acc[r][cdx] = 0.0f;

#pragma unroll
    for (int i = 0; i < 16; i++) {
        const float* wrow = W + (size_t)(k0 + i) * NC;
#pragma unroll
        for (int cdx = 0; cdx < NC; cdx++) {
            float wv = wrow[cdx];
            acc[0][cdx] += hv[0][i] * wv;
            acc[1][cdx] += hv[1][i] * wv;
            acc[2][cdx] += hv[2][i] * wv;
            acc[3][cdx] += hv[3][i] * wv;
        }
    }
#pragma unroll
    for (int r = 0; r < 4; r++)
#pragma unroll
        for (int cdx = 0; cdx < NC; cdx++) {
            float s = acc[r][cdx];
#pragma unroll
            for (int m = 1; m < 64; m <<= 1) s += __shfl_xor(s, m, 64);
            acc[r][cdx] = s;
        }
#pragma unroll
    for (int r = 0; r < 4; r++) {
        float val = 0.0f;
#pragma unroll
        for (int cdx = 0; cdx < NC; cdx++)
            if (lane == cdx) val = acc[r][cdx];
        if (lane < NC) out[(size_t)(r0 + r) * NC + lane] = val + bias[lane];
    }
}

// ------------------------------ launcher -----------------------------------
extern "C" void kernel_launch(void* const* d_in, const int* in_sizes, int n_in,
                              void* d_out, int out_size, void* d_ws, size_t ws_size,
                              hipStream_t stream) {
    const float* x    = (const float*)d_in[0];
    const float* w0f  = (const float*)d_in[1];
    const float* v0f  = (const float*)d_in[2];
    const float* b0f  = (const float*)d_in[3];
    const float* w0b  = (const float*)d_in[4];
    const float* v0b  = (const float*)d_in[5];
    const float* b0b  = (const float*)d_in[6];
    const float* w1f  = (const float*)d_in[7];
    const float* v1f  = (const float*)d_in[8];
    const float* b1f  = (const float*)d_in[9];
    const float* w1b  = (const float*)d_in[10];
    const float* v1b  = (const float*)d_in[11];
    const float* b1b  = (const float*)d_in[12];
    const float* fcw  = (const float*)d_in[13];
    const float* fcb  = (const float*)d_in[14];
    float* out = (float*)d_out;

    char* ws = (char*)d_ws;
    const size_t XB_B = (size_t)T_LEN * D_IN * 2;    // 33.5 MB (also h1)
    const size_t WT_B = (size_t)NU2 * D_IN * 2;      // 6.3 MB per layer (concat f;b)
    const size_t H0_B = (size_t)T_LEN * D_IN * 2;    // 33.5 MB
    const size_t PL_B = (size_t)T_LEN * HDIM * 2;    // 16.8 MB per plane

    size_t off = 0;
    unsigned short* xb  = (unsigned short*)(ws + off); off += XB_B;
    unsigned short* h1  = xb;                             // alias: xb dead after layer-0 scan
    unsigned short* wt0 = (unsigned short*)(ws + off); off += WT_B;
    unsigned short* wt1 = (unsigned short*)(ws + off); off += WT_B;
    unsigned short* h0  = (unsigned short*)(ws + off); off += H0_B;
    unsigned short* P0F = (unsigned short*)(ws + off); off += PL_B;
    unsigned short* P1F = (unsigned short*)(ws + off); off += PL_B;
    unsigned short* P2F = (unsigned short*)(ws + off); off += PL_B;
    unsigned short* P0B = (unsigned short*)(ws + off); off += PL_B;
    unsigned short* P1B = (unsigned short*)(ws + off); off += PL_B;
    unsigned short* P2B = (unsigned short*)(ws + off); off += PL_B;
    // total ~180.5 MB — same footprint class as rounds 3-5 (fit).

    // 1. casts / transposes (f and b write into one concatenated Wt per layer)
    cast_f32_bf16<<<T_LEN * D_IN / 4 / 256, 256, 0, stream>>>(x, xb, (long)T_LEN * D_IN);
    dim3 tb(32, 8);
    dim3 tg(1536 / 32, D_IN / 32);
    transpose_cast<<<tg, tb, 0, stream>>>(w0f, wt0, D_IN, 1536);
    transpose_cast<<<tg, tb, 0, stream>>>(w0b, wt0 + (size_t)1536 * D_IN, D_IN, 1536);
    transpose_cast<<<tg, tb, 0, stream>>>(w1f, wt1, D_IN, 1536);
    transpose_cast<<<tg, tb, 0, stream>>>(w1b, wt1 + (size_t)1536 * D_IN, D_IN, 1536);

    dim3 gg(NU2 / BN, T_LEN / BM);   // x = N-tiles (24) fastest
    dim3 sg(HDIM / 64, NCHUNK / 4, 2);
    dim3 sb(64, 4, 1);

    // 2. layer 0 (x_res read from xb, bf16)
    gemm_fused<<<gg, 256, 0, stream>>>(xb, wt0, P0F, P1F, P2F, P0B, P1B, P2B,
                                       b0f, b0b, T_LEN, D_IN);
    sru_scan<<<sg, sb, 0, stream>>>(P0F, P1F, P2F, P0B, P1B, P2B,
                                    xb, xb + HDIM, v0f, v0b, h0);

    // 3. layer 1 (h1 aliases xb; xb no longer read after layer-0 scan)
    gemm_fused<<<gg, 256, 0, stream>>>(h0, wt1, P0F, P1F, P2F, P0B, P1B, P2B,
                                       b1f, b1b, T_LEN, D_IN);
    sru_scan<<<sg, sb, 0, stream>>>(P0F, P1F, P2F, P0B, P1B, P2B,
                                    h0, h0 + HDIM, v1f, v1b, h1);

    // 4. fc head
    fc_kernel<<<T_LEN / 4 * 64 / 256, 256, 0, stream>>>(h1, fcw, fcb, out);
    (void)in_sizes; (void)n_in; (void)out_size;
}

// Round 7
// 458.807 us; speedup vs baseline: 3.9260x; 1.0131x over previous
//
#include <hip/hip_runtime.h>

// ---------------------------------------------------------------------------
// SRU (2-layer bidirectional, v2 cell) + fc head for MI355X (gfx950).
//   1. cast x (f32 -> bf16)
//   2. transpose+cast weights into ONE concatenated Wt[3072][1024] per layer
//   3. per layer: ONE fused GEMM (N=3072, global_load_lds staging with
//      pre-swizzled source, XCD-aware block swizzle) writing 6 planes
//      (U0,U1',U2' per dir; U1'/U2' have bias and -log2e folded in)
//   4. one scan launch per layer (both dirs), then fc head
// Scan: CHUNK=64, WARM=64, raw-bit rings (convert at consume), warm ring
// issued first, depth 16 main / 8 warm.
// ---------------------------------------------------------------------------

#define T_LEN 16384
#define D_IN 1024
#define HDIM 512
#define NC 15
#define NU2 3072         // both directions' 3*H columns
#define CHUNK 64
#define WARM 64
#define NCHUNK (T_LEN / CHUNK)   // 256
#define L2E 1.44269504f

typedef __attribute__((ext_vector_type(8))) short short8v;
typedef __attribute__((ext_vector_type(4))) float float4v;
typedef __attribute__((ext_vector_type(4))) int int4v;

__device__ __forceinline__ unsigned short f2bf(float f) {
    unsigned u = __float_as_uint(f);
    unsigned r = (u + 0x7FFFu + ((u >> 16) & 1u)) >> 16;
    return (unsigned short)r;
}
__device__ __forceinline__ float bf2f(unsigned s) {
    return __uint_as_float(s << 16);
}
__device__ __forceinline__ float sigm2(float zarg) {   // 1/(1+2^zarg)
    float e = __builtin_amdgcn_exp2f(zarg);
    return __builtin_amdgcn_rcpf(1.0f + e);
}

// async global->LDS, 16 B/lane; LDS dest = wave-uniform base + lane*16
#define GLDS(gp, lp)                                                          \
    __builtin_amdgcn_global_load_lds(                                         \
        (const __attribute__((address_space(1))) unsigned int*)(gp),          \
        (__attribute__((address_space(3))) unsigned int*)(lp), 16, 0, 0)

// -------------------------- cast x to bf16 ---------------------------------
__global__ __launch_bounds__(256) void cast_f32_bf16(const float* __restrict__ in,
                                                     unsigned short* __restrict__ out,
                                                     long n) {
    long i = ((long)blockIdx.x * blockDim.x + threadIdx.x) * 4;
    if (i + 3 < n) {
        float4v v = *(const float4v*)(in + i);
        unsigned short o0 = f2bf(v[0]), o1 = f2bf(v[1]), o2 = f2bf(v[2]), o3 = f2bf(v[3]);
        unsigned short* p = out + i;
        p[0] = o0; p[1] = o1; p[2] = o2; p[3] = o3;
    }
}

// ---------------- transpose + cast weights: [K][N] f32 -> [N][K] bf16 ------
__global__ __launch_bounds__(256) void transpose_cast(const float* __restrict__ w,
                                                      unsigned short* __restrict__ wt,
                                                      int K, int N) {
    __shared__ float tile[32][33];
    int n0 = blockIdx.x * 32, k0 = blockIdx.y * 32;
    int tx = threadIdx.x;   // 0..31
    int ty = threadIdx.y;   // 0..7
#pragma unroll
    for (int i = 0; i < 32; i += 8)
        tile[ty + i][tx] = w[(size_t)(k0 + ty + i) * N + n0 + tx];
    __syncthreads();
#pragma unroll
    for (int i = 0; i < 32; i += 8)
        wt[(size_t)(n0 + ty + i) * K + k0 + tx] = f2bf(tile[tx][ty + i]);
}

// ------------------------------ fused MFMA GEMM ----------------------------
// U[M][3072] = A[M][K] bf16 @ Wt[3072][K] bf16, K = 1024, stored into 6
// planes of [T][512] bf16 (plane = n0>>9, uniform per block).
// 128x128 tile, BK=64, 4 waves (2x2). Staging: global_load_lds dwordx4 with
// PRE-SWIZZLED per-lane global source + linear LDS dest; LDS content is
// LDS[row][cc] = global(row, cc^(row&7)) -> swizzled ds_read_b128 is
// conflict-free and unchanged. XCD-aware bijective block swizzle: XCD k
// owns M-tiles [16k,16k+16), 24 N-blocks consecutive -> A fetched ~once.
#define BM 128
#define BN 128
#define BK 64

__global__ __launch_bounds__(256) void gemm_fused(const unsigned short* __restrict__ A,
                                                  const unsigned short* __restrict__ Bt,
                                                  unsigned short* __restrict__ P0F,
                                                  unsigned short* __restrict__ P1F,
                                                  unsigned short* __restrict__ P2F,
                                                  unsigned short* __restrict__ P0B,
                                                  unsigned short* __restrict__ P1B,
                                                  unsigned short* __restrict__ P2B,
                                                  const float* __restrict__ bias_f,
                                                  const float* __restrict__ bias_b,
                                                  int M, int K) {
    __shared__ int4v lds[(BM * BK + BN * BK) * 2 / 16];
    char* ldsA = (char*)lds;
    char* ldsB = (char*)lds + BM * BK * 2;

    int tid = threadIdx.x;
    // XCD-aware swizzle (bijective: 3072 % 8 == 0):
    int h = blockIdx.y * 24 + blockIdx.x;           // hardware dispatch id
    int w = (h & 7) * 384 + (h >> 3);               // XCD-contiguous work id
    int n0 = (w % 24) * BN;
    int m0 = (w / 24) * BM;

    int wid = tid >> 6, lane = tid & 63;
    int wm = (wid >> 1) * 64, wn = (wid & 1) * 64;
    int l15 = lane & 15, l4 = lane >> 4;
    // pre-swizzled per-lane source offset (elements): row = lane>>3 within
    // 8-row chunk, 16B group cc = (lane&7)^(lane>>3)
    int lsrc = (lane >> 3) * K + (((lane & 7) ^ (lane >> 3)) << 3);

    float4v acc[4][4] = {};

    for (int kt = 0; kt < K; kt += BK) {
        const unsigned short* Ab = A + (size_t)m0 * K + kt;
        const unsigned short* Bb = Bt + (size_t)n0 * K + kt;
        __syncthreads();   // all waves done ds_reading previous tile
#pragma unroll
        for (int i = 0; i < 4; i++) {
            int ck = (wid << 2) + i;                // chunk 0..15 (8 rows each)
            GLDS(Ab + (size_t)ck * 8 * K + lsrc, ldsA + (ck << 10));
            GLDS(Bb + (size_t)ck * 8 * K + lsrc, ldsB + (ck << 10));
        }
        __syncthreads();   // compiler drains vmcnt(0) before barrier -> LDS ready
#pragma unroll
        for (int ks = 0; ks < 2; ks++) {
            short8v af[4], bfr[4];
#pragma unroll
            for (int f = 0; f < 4; f++) {
                int ra = wm + f * 16 + l15;
                int ca = ((ks * 4 + l4) ^ (ra & 7)) * 16;
                af[f] = *(const short8v*)(ldsA + ra * 128 + ca);
                int rb = wn + f * 16 + l15;
                int cb = ((ks * 4 + l4) ^ (rb & 7)) * 16;
                bfr[f] = *(const short8v*)(ldsB + rb * 128 + cb);
            }
#pragma unroll
            for (int fm = 0; fm < 4; fm++)
#pragma unroll
                for (int fn = 0; fn < 4; fn++)
                    acc[fm][fn] = __builtin_amdgcn_mfma_f32_16x16x32_bf16(
                        af[fm], bfr[fn], acc[fm][fn], 0, 0, 0);
        }
    }

    // ---- epilogue: plane select (uniform per block), branch-free fma+store
    int plane = n0 >> 9;   // 0..5
    unsigned short* dst;
    const float* bp;
    if      (plane == 0) { dst = P0F; bp = nullptr; }
    else if (plane == 1) { dst = P1F; bp = bias_f; }
    else if (plane == 2) { dst = P2F; bp = bias_f + HDIM; }
    else if (plane == 3) { dst = P0B; bp = nullptr; }
    else if (plane == 4) { dst = P1B; bp = bias_b; }
    else                 { dst = P2B; bp = bias_b + HDIM; }
    float smul = bp ? -L2E : 1.0f;
    int cip0 = (n0 & 511) + wn;   // col-in-plane base for this wave

    float tadd[4];
#pragma unroll
    for (int fn = 0; fn < 4; fn++)
        tadd[fn] = bp ? -L2E * bp[cip0 + fn * 16 + l15] : 0.0f;

    // D[row=(l>>4)*4+j][col=l&15] per 16x16 frag (m89-verified layout)
#pragma unroll
    for (int fm = 0; fm < 4; fm++) {
        int r0 = m0 + wm + fm * 16 + l4 * 4;
#pragma unroll
        for (int fn = 0; fn < 4; fn++) {
            int chp = cip0 + fn * 16 + l15;
#pragma unroll
            for (int j = 0; j < 4; j++)
                dst[(size_t)(r0 + j) * 512 + chp] =
                    f2bf(fmaf(smul, acc[fm][fn][j], tadd[fn]));
        }
    }
}

// ------------------------------ SRU scan -----------------------------------
// Both directions in one launch (grid.z = 2). Block = (64 ch) x (4 chunks);
// 4096 independent waves. Raw-bit rings, convert at consume. Warm ring
// issued FIRST (vmcnt completes in issue order). Warm = 2 loads/step,
// main = 4 loads/step.
#define DM 16
#define DW 8
__global__ __launch_bounds__(256, 4) void sru_scan(
        const unsigned short* __restrict__ P0f, const unsigned short* __restrict__ P1f,
        const unsigned short* __restrict__ P2f,
        const unsigned short* __restrict__ P0b, const unsigned short* __restrict__ P1b,
        const unsigned short* __restrict__ P2b,
        const unsigned short* __restrict__ xrf, const unsigned short* __restrict__ xrb,
        const float* __restrict__ vF, const float* __restrict__ vB,
        unsigned short* __restrict__ hout) {
    int dir = blockIdx.z;
    int ch = blockIdx.x * 64 + threadIdx.x;
    int cid = blockIdx.y * 4 + threadIdx.y;

    const unsigned short *P0, *P1, *P2, *xr;
    const float* vv;
    int outc;
    if (dir == 0) { P0 = P0f; P1 = P1f; P2 = P2f; xr = xrf; vv = vF; outc = ch; }
    else          { P0 = P0b; P1 = P1b; P2 = P2b; xr = xrb; vv = vB; outc = HDIM + ch; }

    float vfs = -L2E * vv[ch];
    float vrs = -L2E * vv[HDIM + ch];

    int cb = cid * CHUNK;
    int tstep = dir ? -1 : 1;
    int mstart = dir ? cb + CHUNK - 1 : cb;
    int wstart, wn;
    if (dir == 0) {
        wstart = cb - WARM; if (wstart < 0) wstart = 0;
        wn = cb - wstart;
    } else {
        wstart = cb + CHUNK - 1 + WARM; if (wstart > T_LEN - 1) wstart = T_LEN - 1;
        wn = wstart - (cb + CHUNK - 1);
    }

    // warm rings FIRST (oldest loads complete first)
    unsigned w0r[DW], w1r[DW];
#pragma unroll
    for (int d = 0; d < DW; d++) {
        if (d < wn) {
            int t = wstart + tstep * d;
            unsigned bi = (unsigned)t * 512u + ch;
            w0r[d] = P0[bi]; w1r[d] = P1[bi];
        }
    }
    // main rings (hide under whole warm phase)
    unsigned a0[DM], a1[DM], a2[DM], axr[DM];
#pragma unroll
    for (int d = 0; d < DM; d++) {
        int t = mstart + tstep * d;
        unsigned bi = (unsigned)t * 512u + ch;
        a0[d] = P0[bi]; a1[d] = P1[bi]; a2[d] = P2[bi];
        axr[d] = xr[(unsigned)t * 1024u + ch];
    }

    float c = 0.0f;
    // warm-up: state only (wn uniform across the wave)
    for (int nb = 0; nb < wn; nb += DW) {
#pragma unroll
        for (int d = 0; d < DW; d++) {
            int n = nb + d;
            if (n < wn) {
                float u0 = bf2f(w0r[d]);
                float u1s = bf2f(w1r[d]);
                int np = n + DW;
                if (np < wn) {
                    int tp = wstart + tstep * np;
                    unsigned bi = (unsigned)tp * 512u + ch;
                    w0r[d] = P0[bi]; w1r[d] = P1[bi];
                }
                float g1 = sigm2(fmaf(vfs, c, u1s));
                c = u0 + g1 * (c - u0);
            }
        }
    }
    // main: full cell + h write (exactly CHUNK steps, CHUNK % DM == 0)
    for (int nb = 0; nb < CHUNK; nb += DM) {
#pragma unroll
        for (int d = 0; d < DM; d++) {
            int n = nb + d;
            int t = mstart + tstep * n;
            float u0 = bf2f(a0[d]);
            float u1s = bf2f(a1[d]);
            float u2s = bf2f(a2[d]);
            float xv = bf2f(axr[d]);
            int np = n + DM;
            if (np < CHUNK) {
                int tp = mstart + tstep * np;
                unsigned bi = (unsigned)tp * 512u + ch;
                a0[d] = P0[bi]; a1[d] = P1[bi]; a2[d] = P2[bi];
                axr[d] = xr[(unsigned)tp * 1024u + ch];
            }
            float g1 = sigm2(fmaf(vfs, c, u1s));
            c = u0 + g1 * (c - u0);
            float g2 = sigm2(fmaf(vrs, c, u2s));
            float h = xv + g2 * (c - xv);
            hout[(unsigned)t * 1024u + outc] = f2bf(h);
        }
    }
}

// ------------------------------ fc head ------------------------------------
// out[T][15] = h1[T][1024] @ fc_w[1024][15] + fc_b. One wave per 4 rows.
__global__ __launch_bounds__(256) void fc_kernel(const unsigned short* __restrict__ h,
                                                 const float* __restrict__ W,
                                                 const float* __restrict__ bias,
                                                 float* __restrict__ out) {
    int gwid = (int)((blockIdx.x * (size_t)blockDim.x + threadIdx.x) >> 6);
    int lane = threadIdx.x & 63;
    int r0 = gwid * 4;
    int k0 = lane * 16;

    float hv[4][16];
#pragma unroll
    for (int r = 0; r < 4; r++) {
#pragma unroll
        for (int i = 0; i < 16; i += 8) {
            short8v v = *(const short8v*)(h + (size_t)(r0 + r) * D_IN + k0 + i);
#pragma unroll
            for (int j = 0; j < 8; j++)
                hv[r][i + j] = bf2f((unsigned short)v[j]);
        }
    }
    float acc[4][NC];
#pragma unroll
    for (int r = 0; r < 4; r++)
#pragma unroll
        for (int cdx = 0; cdx < NC; cdx++) acc[r][cdx] = 0.0f;

#pragma unroll
    for (int i = 0; i < 16; i++) {
        const float* wrow = W + (size_t)(k0 + i) * NC;
#pragma unroll
        for (int cdx = 0; cdx < NC; cdx++) {
            float wv = wrow[cdx];
            acc[0][cdx] += hv[0][i] * wv;
            acc[1][cdx] += hv[1][i] * wv;
            acc[2][cdx] += hv[2][i] * wv;
            acc[3][cdx] += hv[3][i] * wv;
        }
    }
#pragma unroll
    for (int r = 0; r < 4; r++)
#pragma unroll
        for (int cdx = 0; cdx < NC; cdx++) {
            float s = acc[r][cdx];
#pragma unroll
            for (int m = 1; m < 64; m <<= 1) s += __shfl_xor(s, m, 64);
            acc[r][cdx] = s;
        }
#pragma unroll
    for (int r = 0; r < 4; r++) {
        float val = 0.0f;
#pragma unroll
        for (int cdx = 0; cdx < NC; cdx++)
            if (lane == cdx) val = acc[r][cdx];
        if (lane < NC) out[(size_t)(r0 + r) * NC + lane] = val + bias[lane];
    }
}

// ------------------------------ launcher -----------------------------------
extern "C" void kernel_launch(void* const* d_in, const int* in_sizes, int n_in,
                              void* d_out, int out_size, void* d_ws, size_t ws_size,
                              hipStream_t stream) {
    const float* x    = (const float*)d_in[0];
    const float* w0f  = (const float*)d_in[1];
    const float* v0f  = (const float*)d_in[2];
    const float* b0f  = (const float*)d_in[3];
    const float* w0b  = (const float*)d_in[4];
    const float* v0b  = (const float*)d_in[5];
    const float* b0b  = (const float*)d_in[6];
    const float* w1f  = (const float*)d_in[7];
    const float* v1f  = (const float*)d_in[8];
    const float* b1f  = (const float*)d_in[9];
    const float* w1b  = (const float*)d_in[10];
    const float* v1b  = (const float*)d_in[11];
    const float* b1b  = (const float*)d_in[12];
    const float* fcw  = (const float*)d_in[13];
    const float* fcb  = (const float*)d_in[14];
    float* out = (float*)d_out;

    char* ws = (char*)d_ws;
    const size_t XB_B = (size_t)T_LEN * D_IN * 2;    // 33.5 MB (also h1)
    const size_t WT_B = (size_t)NU2 * D_IN * 2;      // 6.3 MB per layer (concat f;b)
    const size_t H0_B = (size_t)T_LEN * D_IN * 2;    // 33.5 MB
    const size_t PL_B = (size_t)T_LEN * HDIM * 2;    // 16.8 MB per plane

    size_t off = 0;
    unsigned short* xb  = (unsigned short*)(ws + off); off += XB_B;
    unsigned short* h1  = xb;                             // alias: xb dead after layer-0 scan
    unsigned short* wt0 = (unsigned short*)(ws + off); off += WT_B;
    unsigned short* wt1 = (unsigned short*)(ws + off); off += WT_B;
    unsigned short* h0  = (unsigned short*)(ws + off); off += H0_B;
    unsigned short* P0F = (unsigned short*)(ws + off); off += PL_B;
    unsigned short* P1F = (unsigned short*)(ws + off); off += PL_B;
    unsigned short* P2F = (unsigned short*)(ws + off); off += PL_B;
    unsigned short* P0B = (unsigned short*)(ws + off); off += PL_B;
    unsigned short* P1B = (unsigned short*)(ws + off); off += PL_B;
    unsigned short* P2B = (unsigned short*)(ws + off); off += PL_B;
    // total ~180.5 MB — same footprint class as rounds 3-6 (fit).

    // 1. casts / transposes (f and b write into one concatenated Wt per layer)
    cast_f32_bf16<<<T_LEN * D_IN / 4 / 256, 256, 0, stream>>>(x, xb, (long)T_LEN * D_IN);
    dim3 tb(32, 8);
    dim3 tg(1536 / 32, D_IN / 32);
    transpose_cast<<<tg, tb, 0, stream>>>(w0f, wt0, D_IN, 1536);
    transpose_cast<<<tg, tb, 0, stream>>>(w0b, wt0 + (size_t)1536 * D_IN, D_IN, 1536);
    transpose_cast<<<tg, tb, 0, stream>>>(w1f, wt1, D_IN, 1536);
    transpose_cast<<<tg, tb, 0, stream>>>(w1b, wt1 + (size_t)1536 * D_IN, D_IN, 1536);

    dim3 gg(NU2 / BN, T_LEN / BM);   // remapped in-kernel (XCD swizzle)
    dim3 sg(HDIM / 64, NCHUNK / 4, 2);
    dim3 sb(64, 4, 1);

    // 2. layer 0 (x_res read from xb, bf16)
    gemm_fused<<<gg, 256, 0, stream>>>(xb, wt0, P0F, P1F, P2F, P0B, P1B, P2B,
                                       b0f, b0b, T_LEN, D_IN);
    sru_scan<<<sg, sb, 0, stream>>>(P0F, P1F, P2F, P0B, P1B, P2B,
                                    xb, xb + HDIM, v0f, v0b, h0);

    // 3. layer 1 (h1 aliases xb; xb no longer read after layer-0 scan)
    gemm_fused<<<gg, 256, 0, stream>>>(h0, wt1, P0F, P1F, P2F, P0B, P1B, P2B,
                                       b1f, b1b, T_LEN, D_IN);
    sru_scan<<<sg, sb, 0, stream>>>(P0F, P1F, P2F, P0B, P1B, P2B,
                                    h0, h0 + HDIM, v1f, v1b, h1);

    // 4. fc head
    fc_kernel<<<T_LEN / 4 * 64 / 256, 256, 0, stream>>>(h1, fcw, fcb, out);
    (void)in_sizes; (void)n_in; (void)out_size;
}

// Round 8
// 421.032 us; speedup vs baseline: 4.2782x; 1.0897x over previous
//
#include <hip/hip_runtime.h>

// ---------------------------------------------------------------------------
// SRU (2-layer bidirectional, v2 cell) + fc head for MI355X (gfx950).
//   1. cast x (f32 -> bf16)
//   2. transpose+cast weights into ONE concatenated Wt[3072][1024] per layer
//   3. per layer: ONE fused 256x256-tile pipelined GEMM (8 waves, 4-slot LDS
//      ring, counted vmcnt(4), setprio MFMA clusters) writing 6 planes
//      (U0,U1',U2' per dir; U1'/U2' have bias and -log2e folded in)
//   4. one scan launch per layer (both dirs), then fc head
// ---------------------------------------------------------------------------

#define T_LEN 16384
#define D_IN 1024
#define HDIM 512
#define NC 15
#define NU2 3072         // both directions' 3*H columns
#define CHUNK 64
#define WARM 64
#define NCHUNK (T_LEN / CHUNK)   // 256
#define L2E 1.44269504f

typedef __attribute__((ext_vector_type(8))) short short8v;
typedef __attribute__((ext_vector_type(4))) float float4v;
typedef __attribute__((ext_vector_type(4))) int int4v;

__device__ __forceinline__ unsigned short f2bf(float f) {
    unsigned u = __float_as_uint(f);
    unsigned r = (u + 0x7FFFu + ((u >> 16) & 1u)) >> 16;
    return (unsigned short)r;
}
__device__ __forceinline__ float bf2f(unsigned s) {
    return __uint_as_float(s << 16);
}
__device__ __forceinline__ float sigm2(float zarg) {   // 1/(1+2^zarg)
    float e = __builtin_amdgcn_exp2f(zarg);
    return __builtin_amdgcn_rcpf(1.0f + e);
}

// async global->LDS, 16 B/lane; LDS dest = wave-uniform base + lane*16
#define GLDS(gp, lp)                                                          \
    __builtin_amdgcn_global_load_lds(                                         \
        (const __attribute__((address_space(1))) unsigned int*)(gp),          \
        (__attribute__((address_space(3))) unsigned int*)(lp), 16, 0, 0)

// -------------------------- cast x to bf16 ---------------------------------
__global__ __launch_bounds__(256) void cast_f32_bf16(const float* __restrict__ in,
                                                     unsigned short* __restrict__ out,
                                                     long n) {
    long i = ((long)blockIdx.x * blockDim.x + threadIdx.x) * 4;
    if (i + 3 < n) {
        float4v v = *(const float4v*)(in + i);
        unsigned short o0 = f2bf(v[0]), o1 = f2bf(v[1]), o2 = f2bf(v[2]), o3 = f2bf(v[3]);
        unsigned short* p = out + i;
        p[0] = o0; p[1] = o1; p[2] = o2; p[3] = o3;
    }
}

// ---------------- transpose + cast weights: [K][N] f32 -> [N][K] bf16 ------
__global__ __launch_bounds__(256) void transpose_cast(const float* __restrict__ w,
                                                      unsigned short* __restrict__ wt,
                                                      int K, int N) {
    __shared__ float tile[32][33];
    int n0 = blockIdx.x * 32, k0 = blockIdx.y * 32;
    int tx = threadIdx.x;   // 0..31
    int ty = threadIdx.y;   // 0..7
#pragma unroll
    for (int i = 0; i < 32; i += 8)
        tile[ty + i][tx] = w[(size_t)(k0 + ty + i) * N + n0 + tx];
    __syncthreads();
#pragma unroll
    for (int i = 0; i < 32; i += 8)
        wt[(size_t)(n0 + ty + i) * K + k0 + tx] = f2bf(tile[tx][ty + i]);
}

// ------------------------- pipelined 256x256 GEMM --------------------------
// U[M][3072] = A[M][1024] bf16 @ Wt[3072][1024] bf16 -> 6 planes [T][512].
// 512 thr = 8 waves (2 M x 4 N), per-wave 128x64 out = acc[8][4] 16x16 frags.
// K-tile = BK=32. LDS ring: 4 slots x (A 16KB + B 16KB) = 128 KB.
// Schedule per K-tile t: [vmcnt(4); s_barrier] phaseA{ds_read B n0-3 + A m0-3,
// GLDS A(t+2), 16 MFMA in setprio} s_barrier phaseB{ds_read A m4-7,
// GLDS B(t+2), 16 MFMA}. Stage distance 2 K-tiles; loads for t+1 stay in
// flight across barriers (never vmcnt(0) in the loop).
// Swizzle: LDS[r][c'] holds global chunk c = c' ^ (r&3) ^ ((r>>2)&3)
// (pre-swizzled global src + linear GLDS dest + swizzled ds_read).
#define GBM 256
#define GBN 256
#define GBK 32
#define SLOT_B 32768     // A 16KB + B 16KB per slot

__global__ __launch_bounds__(512, 2) void gemm_pipe(const unsigned short* __restrict__ A,
                                                    const unsigned short* __restrict__ Bt,
                                                    unsigned short* __restrict__ P0F,
                                                    unsigned short* __restrict__ P1F,
                                                    unsigned short* __restrict__ P2F,
                                                    unsigned short* __restrict__ P0B,
                                                    unsigned short* __restrict__ P1B,
                                                    unsigned short* __restrict__ P2B,
                                                    const float* __restrict__ bias_f,
                                                    const float* __restrict__ bias_b) {
    extern __shared__ char smem[];
    const int K = 1024;

    int tid = threadIdx.x;
    // XCD swizzle: 768 blocks, XCD k owns m-tiles [8k,8k+8); n outer, m inner
    // -> per-XCD A chunk (8*256 rows = 4.2 MB) L2-resident across the n sweep.
    int h = blockIdx.x;
    int w = (h & 7) * 96 + (h >> 3);
    int xcd = w / 96, lw = w % 96;
    int m0 = (xcd * 8 + (lw & 7)) * GBM;
    int n0 = (lw >> 3) * GBN;

    int wid = tid >> 6, lane = tid & 63;
    int wr = wid >> 2, wc = wid & 3;
    int l15 = lane & 15, l4 = lane >> 4;

    // staging source (per-thread): row-in-tile rr, swizzled chunk cs (elements)
    int rr = tid >> 2;
    int cs = (((tid & 3) ^ (rr & 3) ^ ((rr >> 2) & 3)) << 3);
    size_t asrc = (size_t)(m0 + rr) * K + cs;
    size_t bsrc = (size_t)(n0 + rr) * K + cs;
    int ldst = wid << 10;                 // wave-uniform LDS byte base (+lane*16 by HW)

    // ds_read bases: chunkoff constant per lane across all frags
    int chko = ((l4 ^ (l15 & 3) ^ ((l15 >> 2) & 3)) << 4);
    int base_a = (wr * 128 + l15) * 64 + chko;            // in A region
    int base_b = 16384 + (wc * 64 + l15) * 64 + chko;     // in B region

    // prologue: stage K-tiles 0,1 into slots 0,1 (A then B per tile)
#pragma unroll
    for (int t = 0; t < 2; ++t) {
        char* sb = smem + t * SLOT_B;
        GLDS(A + asrc + (size_t)t * GBK, sb + ldst);
        GLDS(A + asrc + (size_t)128 * K + (size_t)t * GBK, sb + 8192 + ldst);
        GLDS(Bt + bsrc + (size_t)t * GBK, sb + 16384 + ldst);
        GLDS(Bt + bsrc + (size_t)128 * K + (size_t)t * GBK, sb + 16384 + 8192 + ldst);
    }

    float4v acc[8][4] = {};
    short8v bfr[4], af[4];

    for (int t = 0; t < 32; ++t) {
        asm volatile("s_waitcnt vmcnt(4)" ::: "memory");
        __builtin_amdgcn_s_barrier();
        char* sb = smem + (t & 3) * SLOT_B;
        int tn = (t + 2) & 31;                   // wrap: stale-slot restage keeps count uniform
        char* sn = smem + (tn & 3) * SLOT_B;

        // ---- phase A: B frags n0-3, A frags m0-3; stage A(t+2)
#pragma unroll
        for (int n = 0; n < 4; ++n)
            bfr[n] = *(const short8v*)(sb + base_b + n * 1024);
#pragma unroll
        for (int m = 0; m < 4; ++m)
            af[m] = *(const short8v*)(sb + base_a + m * 1024);
        GLDS(A + asrc + (size_t)tn * GBK, sn + ldst);
        GLDS(A + asrc + (size_t)128 * K + (size_t)tn * GBK, sn + 8192 + ldst);
        __builtin_amdgcn_s_setprio(1);
#pragma unroll
        for (int m = 0; m < 4; ++m)
#pragma unroll
            for (int n = 0; n < 4; ++n)
                acc[m][n] = __builtin_amdgcn_mfma_f32_16x16x32_bf16(
                    af[m], bfr[n], acc[m][n], 0, 0, 0);
        __builtin_amdgcn_s_setprio(0);
        __builtin_amdgcn_s_barrier();

        // ---- phase B: A frags m4-7 (B reused); stage B(t+2)
#pragma unroll
        for (int m = 0; m < 4; ++m)
            af[m] = *(const short8v*)(sb + base_a + (m + 4) * 1024);
        GLDS(Bt + bsrc + (size_t)tn * GBK, sn + 16384 + ldst);
        GLDS(Bt + bsrc + (size_t)128 * K + (size_t)tn * GBK, sn + 16384 + 8192 + ldst);
        __builtin_amdgcn_s_setprio(1);
#pragma unroll
        for (int m = 0; m < 4; ++m)
#pragma unroll
            for (int n = 0; n < 4; ++n)
                acc[m + 4][n] = __builtin_amdgcn_mfma_f32_16x16x32_bf16(
                    af[m], bfr[n], acc[m + 4][n], 0, 0, 0);
        __builtin_amdgcn_s_setprio(0);
    }

    // ---- epilogue: plane select (uniform per block: BN=256 within one plane)
    int plane = n0 >> 9;   // 0..5
    unsigned short* dst;
    const float* bp;
    if      (plane == 0) { dst = P0F; bp = nullptr; }
    else if (plane == 1) { dst = P1F; bp = bias_f; }
    else if (plane == 2) { dst = P2F; bp = bias_f + HDIM; }
    else if (plane == 3) { dst = P0B; bp = nullptr; }
    else if (plane == 4) { dst = P1B; bp = bias_b; }
    else                 { dst = P2B; bp = bias_b + HDIM; }
    float smul = bp ? -L2E : 1.0f;
    int cip0 = (n0 & 511) + wc * 64;

    float tadd[4];
#pragma unroll
    for (int fn = 0; fn < 4; ++fn)
        tadd[fn] = bp ? -L2E * bp[cip0 + fn * 16 + l15] : 0.0f;

    // D[row=(l>>4)*4+j][col=l&15] per 16x16 frag (m89-verified layout)
#pragma unroll
    for (int fm = 0; fm < 8; ++fm) {
        int r0 = m0 + wr * 128 + fm * 16 + l4 * 4;
#pragma unroll
        for (int fn = 0; fn < 4; ++fn) {
            int chp = cip0 + fn * 16 + l15;
#pragma unroll
            for (int j = 0; j < 4; ++j)
                dst[(size_t)(r0 + j) * 512 + chp] =
                    f2bf(fmaf(smul, acc[fm][fn][j], tadd[fn]));
        }
    }
}

// ------------------------------ SRU scan -----------------------------------
// Both directions in one launch (grid.z = 2). Block = (64 ch) x (4 chunks);
// 4096 independent waves. Raw-bit rings, convert at consume. Warm ring
// issued FIRST (vmcnt completes in issue order).
#define DM 16
#define DW 8
__global__ __launch_bounds__(256, 4) void sru_scan(
        const unsigned short* __restrict__ P0f, const unsigned short* __restrict__ P1f,
        const unsigned short* __restrict__ P2f,
        const unsigned short* __restrict__ P0b, const unsigned short* __restrict__ P1b,
        const unsigned short* __restrict__ P2b,
        const unsigned short* __restrict__ xrf, const unsigned short* __restrict__ xrb,
        const float* __restrict__ vF, const float* __restrict__ vB,
        unsigned short* __restrict__ hout) {
    int dir = blockIdx.z;
    int ch = blockIdx.x * 64 + threadIdx.x;
    int cid = blockIdx.y * 4 + threadIdx.y;

    const unsigned short *P0, *P1, *P2, *xr;
    const float* vv;
    int outc;
    if (dir == 0) { P0 = P0f; P1 = P1f; P2 = P2f; xr = xrf; vv = vF; outc = ch; }
    else          { P0 = P0b; P1 = P1b; P2 = P2b; xr = xrb; vv = vB; outc = HDIM + ch; }

    float vfs = -L2E * vv[ch];
    float vrs = -L2E * vv[HDIM + ch];

    int cb = cid * CHUNK;
    int tstep = dir ? -1 : 1;
    int mstart = dir ? cb + CHUNK - 1 : cb;
    int wstart, wn;
    if (dir == 0) {
        wstart = cb - WARM; if (wstart < 0) wstart = 0;
        wn = cb - wstart;
    } else {
        wstart = cb + CHUNK - 1 + WARM; if (wstart > T_LEN - 1) wstart = T_LEN - 1;
        wn = wstart - (cb + CHUNK - 1);
    }

    // warm rings FIRST (oldest loads complete first)
    unsigned w0r[DW], w1r[DW];
#pragma unroll
    for (int d = 0; d < DW; d++) {
        if (d < wn) {
            int t = wstart + tstep * d;
            unsigned bi = (unsigned)t * 512u + ch;
            w0r[d] = P0[bi]; w1r[d] = P1[bi];
        }
    }
    // main rings (hide under whole warm phase)
    unsigned a0[DM], a1[DM], a2[DM], axr[DM];
#pragma unroll
    for (int d = 0; d < DM; d++) {
        int t = mstart + tstep * d;
        unsigned bi = (unsigned)t * 512u + ch;
        a0[d] = P0[bi]; a1[d] = P1[bi]; a2[d] = P2[bi];
        axr[d] = xr[(unsigned)t * 1024u + ch];
    }

    float c = 0.0f;
    // warm-up: state only (wn uniform across the wave)
    for (int nb = 0; nb < wn; nb += DW) {
#pragma unroll
        for (int d = 0; d < DW; d++) {
            int n = nb + d;
            if (n < wn) {
                float u0 = bf2f(w0r[d]);
                float u1s = bf2f(w1r[d]);
                int np = n + DW;
                if (np < wn) {
                    int tp = wstart + tstep * np;
                    unsigned bi = (unsigned)tp * 512u + ch;
                    w0r[d] = P0[bi]; w1r[d] = P1[bi];
                }
                float g1 = sigm2(fmaf(vfs, c, u1s));
                c = u0 + g1 * (c - u0);
            }
        }
    }
    // main: full cell + h write (exactly CHUNK steps)
    for (int nb = 0; nb < CHUNK; nb += DM) {
#pragma unroll
        for (int d = 0; d < DM; d++) {
            int n = nb + d;
            int t = mstart + tstep * n;
            float u0 = bf2f(a0[d]);
            float u1s = bf2f(a1[d]);
            float u2s = bf2f(a2[d]);
            float xv = bf2f(axr[d]);
            int np = n + DM;
            if (np < CHUNK) {
                int tp = mstart + tstep * np;
                unsigned bi = (unsigned)tp * 512u + ch;
                a0[d] = P0[bi]; a1[d] = P1[bi]; a2[d] = P2[bi];
                axr[d] = xr[(unsigned)tp * 1024u + ch];
            }
            float g1 = sigm2(fmaf(vfs, c, u1s));
            c = u0 + g1 * (c - u0);
            float g2 = sigm2(fmaf(vrs, c, u2s));
            float h = xv + g2 * (c - xv);
            hout[(unsigned)t * 1024u + outc] = f2bf(h);
        }
    }
}

// ------------------------------ fc head ------------------------------------
__global__ __launch_bounds__(256) void fc_kernel(const unsigned short* __restrict__ h,
                                                 const float* __restrict__ W,
                                                 const float* __restrict__ bias,
                                                 float* __restrict__ out) {
    int gwid = (int)((blockIdx.x * (size_t)blockDim.x + threadIdx.x) >> 6);
    int lane = threadIdx.x & 63;
    int r0 = gwid * 4;
    int k0 = lane * 16;

    float hv[4][16];
#pragma unroll
    for (int r = 0; r < 4; r++) {
#pragma unroll
        for (int i = 0; i < 16; i += 8) {
            short8v v = *(const short8v*)(h + (size_t)(r0 + r) * D_IN + k0 + i);
#pragma unroll
            for (int j = 0; j < 8; j++)
                hv[r][i + j] = bf2f((unsigned short)v[j]);
        }
    }
    float acc[4][NC];
#pragma unroll
    for (int r = 0; r < 4; r++)
#pragma unroll
        for (int cdx = 0; cdx < NC; cdx++) acc[r][cdx] = 0.0f;

#pragma unroll
    for (int i = 0; i < 16; i++) {
        const float* wrow = W + (size_t)(k0 + i) * NC;
#pragma unroll
        for (int cdx = 0; cdx < NC; cdx++) {
            float wv = wrow[cdx];
            acc[0][cdx] += hv[0][i] * wv;
            acc[1][cdx] += hv[1][i] * wv;
            acc[2][cdx] += hv[2][i] * wv;
            acc[3][cdx] += hv[3][i] * wv;
        }
    }
#pragma unroll
    for (int r = 0; r < 4; r++)
#pragma unroll
        for (int cdx = 0; cdx < NC; cdx++) {
            float s = acc[r][cdx];
#pragma unroll
            for (int m = 1; m < 64; m <<= 1) s += __shfl_xor(s, m, 64);
            acc[r][cdx] = s;
        }
#pragma unroll
    for (int r = 0; r < 4; r++) {
        float val = 0.0f;
#pragma unroll
        for (int cdx = 0; cdx < NC; cdx++)
            if (lane == cdx) val = acc[r][cdx];
        if (lane < NC) out[(size_t)(r0 + r) * NC + lane] = val + bias[lane];
    }
}

// ------------------------------ launcher -----------------------------------
extern "C" void kernel_launch(void* const* d_in, const int* in_sizes, int n_in,
                              void* d_out, int out_size, void* d_ws, size_t ws_size,
                              hipStream_t stream) {
    const float* x    = (const float*)d_in[0];
    const float* w0f  = (const float*)d_in[1];
    const float* v0f  = (const float*)d_in[2];
    const float* b0f  = (const float*)d_in[3];
    const float* w0b  = (const float*)d_in[4];
    const float* v0b  = (const float*)d_in[5];
    const float* b0b  = (const float*)d_in[6];
    const float* w1f  = (const float*)d_in[7];
    const float* v1f  = (const float*)d_in[8];
    const float* b1f  = (const float*)d_in[9];
    const float* w1b  = (const float*)d_in[10];
    const float* v1b  = (const float*)d_in[11];
    const float* b1b  = (const float*)d_in[12];
    const float* fcw  = (const float*)d_in[13];
    const float* fcb  = (const float*)d_in[14];
    float* out = (float*)d_out;

    char* ws = (char*)d_ws;
    const size_t XB_B = (size_t)T_LEN * D_IN * 2;    // 33.5 MB (also h1)
    const size_t WT_B = (size_t)NU2 * D_IN * 2;      // 6.3 MB per layer
    const size_t H0_B = (size_t)T_LEN * D_IN * 2;    // 33.5 MB
    const size_t PL_B = (size_t)T_LEN * HDIM * 2;    // 16.8 MB per plane

    size_t off = 0;
    unsigned short* xb  = (unsigned short*)(ws + off); off += XB_B;
    unsigned short* h1  = xb;                             // alias: xb dead after layer-0 scan
    unsigned short* wt0 = (unsigned short*)(ws + off); off += WT_B;
    unsigned short* wt1 = (unsigned short*)(ws + off); off += WT_B;
    unsigned short* h0  = (unsigned short*)(ws + off); off += H0_B;
    unsigned short* P0F = (unsigned short*)(ws + off); off += PL_B;
    unsigned short* P1F = (unsigned short*)(ws + off); off += PL_B;
    unsigned short* P2F = (unsigned short*)(ws + off); off += PL_B;
    unsigned short* P0B = (unsigned short*)(ws + off); off += PL_B;
    unsigned short* P1B = (unsigned short*)(ws + off); off += PL_B;
    unsigned short* P2B = (unsigned short*)(ws + off); off += PL_B;
    // total ~180.5 MB — same footprint class as rounds 3-7 (fit).

    // 1. casts / transposes
    cast_f32_bf16<<<T_LEN * D_IN / 4 / 256, 256, 0, stream>>>(x, xb, (long)T_LEN * D_IN);
    dim3 tb(32, 8);
    dim3 tg(1536 / 32, D_IN / 32);
    transpose_cast<<<tg, tb, 0, stream>>>(w0f, wt0, D_IN, 1536);
    transpose_cast<<<tg, tb, 0, stream>>>(w0b, wt0 + (size_t)1536 * D_IN, D_IN, 1536);
    transpose_cast<<<tg, tb, 0, stream>>>(w1f, wt1, D_IN, 1536);
    transpose_cast<<<tg, tb, 0, stream>>>(w1b, wt1 + (size_t)1536 * D_IN, D_IN, 1536);

    dim3 gg((T_LEN / GBM) * (NU2 / GBN));   // 64*12 = 768 blocks, swizzled in-kernel
    dim3 sg(HDIM / 64, NCHUNK / 4, 2);
    dim3 sb(64, 4, 1);

    // 2. layer 0 (x_res read from xb, bf16)
    gemm_pipe<<<gg, 512, 4 * SLOT_B, stream>>>(xb, wt0, P0F, P1F, P2F, P0B, P1B, P2B,
                                               b0f, b0b);
    sru_scan<<<sg, sb, 0, stream>>>(P0F, P1F, P2F, P0B, P1B, P2B,
                                    xb, xb + HDIM, v0f, v0b, h0);

    // 3. layer 1 (h1 aliases xb; xb no longer read after layer-0 scan)
    gemm_pipe<<<gg, 512, 4 * SLOT_B, stream>>>(h0, wt1, P0F, P1F, P2F, P0B, P1B, P2B,
                                               b1f, b1b);
    sru_scan<<<sg, sb, 0, stream>>>(P0F, P1F, P2F, P0B, P1B, P2B,
                                    h0, h0 + HDIM, v1f, v1b, h1);

    // 4. fc head
    fc_kernel<<<T_LEN / 4 * 64 / 256, 256, 0, stream>>>(h1, fcw, fcb, out);
    (void)in_sizes; (void)n_in; (void)out_size;
}

// Round 9
// 365.800 us; speedup vs baseline: 4.9242x; 1.1510x over previous
//
#include <hip/hip_runtime.h>

// ---------------------------------------------------------------------------
// SRU (2-layer bidirectional, v2 cell) + fc head for MI355X (gfx950).
//   1. cast x (f32 -> bf16)
//   2. transpose+cast weights into ONE concatenated Wt[3072][1024] per layer
//   3. per layer: ONE fused 256x256-tile pipelined GEMM (8 waves, 4-slot LDS
//      ring, counted vmcnt(4), setprio MFMA clusters) writing packed planes:
//      P01 (u0 | -L2E*(u1+bf) per dword) and P2 (-L2E*(u2+br)) per direction
//   4. one scan launch per layer (both dirs; 3 main streams + 1 warm stream,
//      peak 56 outstanding loads < 63 vmcnt limit), then fc head
// ---------------------------------------------------------------------------

#define T_LEN 16384
#define D_IN 1024
#define HDIM 512
#define NC 15
#define NU2 3072         // both directions' 3*H columns
#define CHUNK 64
#define WARM 64
#define NCHUNK (T_LEN / CHUNK)   // 256
#define L2E 1.44269504f

typedef __attribute__((ext_vector_type(8))) short short8v;
typedef __attribute__((ext_vector_type(4))) float float4v;
typedef __attribute__((ext_vector_type(4))) int int4v;

__device__ __forceinline__ unsigned short f2bf(float f) {
    unsigned u = __float_as_uint(f);
    unsigned r = (u + 0x7FFFu + ((u >> 16) & 1u)) >> 16;
    return (unsigned short)r;
}
__device__ __forceinline__ float bf2f(unsigned s) {
    return __uint_as_float(s << 16);
}
__device__ __forceinline__ float sigm2(float zarg) {   // 1/(1+2^zarg)
    float e = __builtin_amdgcn_exp2f(zarg);
    return __builtin_amdgcn_rcpf(1.0f + e);
}

// async global->LDS, 16 B/lane; LDS dest = wave-uniform base + lane*16
#define GLDS(gp, lp)                                                          \
    __builtin_amdgcn_global_load_lds(                                         \
        (const __attribute__((address_space(1))) unsigned int*)(gp),          \
        (__attribute__((address_space(3))) unsigned int*)(lp), 16, 0, 0)

// -------------------------- cast x to bf16 ---------------------------------
__global__ __launch_bounds__(256) void cast_f32_bf16(const float* __restrict__ in,
                                                     unsigned short* __restrict__ out,
                                                     long n) {
    long i = ((long)blockIdx.x * blockDim.x + threadIdx.x) * 4;
    if (i + 3 < n) {
        float4v v = *(const float4v*)(in + i);
        unsigned short o0 = f2bf(v[0]), o1 = f2bf(v[1]), o2 = f2bf(v[2]), o3 = f2bf(v[3]);
        unsigned short* p = out + i;
        p[0] = o0; p[1] = o1; p[2] = o2; p[3] = o3;
    }
}

// ---------------- transpose + cast weights: [K][N] f32 -> [N][K] bf16 ------
__global__ __launch_bounds__(256) void transpose_cast(const float* __restrict__ w,
                                                      unsigned short* __restrict__ wt,
                                                      int K, int N) {
    __shared__ float tile[32][33];
    int n0 = blockIdx.x * 32, k0 = blockIdx.y * 32;
    int tx = threadIdx.x;   // 0..31
    int ty = threadIdx.y;   // 0..7
#pragma unroll
    for (int i = 0; i < 32; i += 8)
        tile[ty + i][tx] = w[(size_t)(k0 + ty + i) * N + n0 + tx];
    __syncthreads();
#pragma unroll
    for (int i = 0; i < 32; i += 8)
        wt[(size_t)(n0 + ty + i) * K + k0 + tx] = f2bf(tile[tx][ty + i]);
}

// ------------------------- pipelined 256x256 GEMM --------------------------
// U[M][3072] = A[M][1024] bf16 @ Wt[3072][1024] bf16.
// 512 thr = 8 waves (2 M x 4 N), per-wave 128x64 out = acc[8][4] 16x16 frags.
// K-tile = BK=32. LDS ring: 4 slots x (A 16KB + B 16KB) = 128 KB.
// Counted vmcnt(4) + s_barrier at K-tile top; stage distance 2; setprio
// around MFMA clusters. Swizzle: LDS[r][c'] = global chunk c'^(r&3)^((r>>2)&3)
// via pre-swizzled global src + linear GLDS dest + swizzled ds_read.
// Epilogue planes: 0->P01F lo, 1->P01F hi, 2->P2F, 3->P01B lo, 4->P01B hi,
// 5->P2B (stride-2 ushort stores for the P01 planes).
#define GBM 256
#define GBN 256
#define GBK 32
#define SLOT_B 32768     // A 16KB + B 16KB per slot

__global__ __launch_bounds__(512, 2) void gemm_pipe(const unsigned short* __restrict__ A,
                                                    const unsigned short* __restrict__ Bt,
                                                    unsigned short* __restrict__ P01F,
                                                    unsigned short* __restrict__ P2F,
                                                    unsigned short* __restrict__ P01B,
                                                    unsigned short* __restrict__ P2B,
                                                    const float* __restrict__ bias_f,
                                                    const float* __restrict__ bias_b) {
    extern __shared__ char smem[];
    const int K = 1024;

    int tid = threadIdx.x;
    // XCD swizzle: 768 blocks, XCD k owns m-tiles [8k,8k+8); n outer, m inner
    int h = blockIdx.x;
    int w = (h & 7) * 96 + (h >> 3);
    int xcd = w / 96, lw = w % 96;
    int m0 = (xcd * 8 + (lw & 7)) * GBM;
    int n0 = (lw >> 3) * GBN;

    int wid = tid >> 6, lane = tid & 63;
    int wr = wid >> 2, wc = wid & 3;
    int l15 = lane & 15, l4 = lane >> 4;

    // staging source (per-thread): row-in-tile rr, swizzled chunk cs (elements)
    int rr = tid >> 2;
    int cs = (((tid & 3) ^ (rr & 3) ^ ((rr >> 2) & 3)) << 3);
    size_t asrc = (size_t)(m0 + rr) * K + cs;
    size_t bsrc = (size_t)(n0 + rr) * K + cs;
    int ldst = wid << 10;                 // wave-uniform LDS byte base (+lane*16 by HW)

    // ds_read bases: chunkoff constant per lane across all frags
    int chko = ((l4 ^ (l15 & 3) ^ ((l15 >> 2) & 3)) << 4);
    int base_a = (wr * 128 + l15) * 64 + chko;            // in A region
    int base_b = 16384 + (wc * 64 + l15) * 64 + chko;     // in B region

    // prologue: stage K-tiles 0,1 into slots 0,1 (A then B per tile)
#pragma unroll
    for (int t = 0; t < 2; ++t) {
        char* sb = smem + t * SLOT_B;
        GLDS(A + asrc + (size_t)t * GBK, sb + ldst);
        GLDS(A + asrc + (size_t)128 * K + (size_t)t * GBK, sb + 8192 + ldst);
        GLDS(Bt + bsrc + (size_t)t * GBK, sb + 16384 + ldst);
        GLDS(Bt + bsrc + (size_t)128 * K + (size_t)t * GBK, sb + 16384 + 8192 + ldst);
    }

    float4v acc[8][4] = {};
    short8v bfr[4], af[4];

    for (int t = 0; t < 32; ++t) {
        asm volatile("s_waitcnt vmcnt(4)" ::: "memory");
        __builtin_amdgcn_s_barrier();
        char* sb = smem + (t & 3) * SLOT_B;
        int tn = (t + 2) & 31;                   // wrap: stale-slot restage keeps count uniform
        char* sn = smem + (tn & 3) * SLOT_B;

        // ---- phase A: B frags n0-3, A frags m0-3; stage A(t+2)
#pragma unroll
        for (int n = 0; n < 4; ++n)
            bfr[n] = *(const short8v*)(sb + base_b + n * 1024);
#pragma unroll
        for (int m = 0; m < 4; ++m)
            af[m] = *(const short8v*)(sb + base_a + m * 1024);
        GLDS(A + asrc + (size_t)tn * GBK, sn + ldst);
        GLDS(A + asrc + (size_t)128 * K + (size_t)tn * GBK, sn + 8192 + ldst);
        __builtin_amdgcn_s_setprio(1);
#pragma unroll
        for (int m = 0; m < 4; ++m)
#pragma unroll
            for (int n = 0; n < 4; ++n)
                acc[m][n] = __builtin_amdgcn_mfma_f32_16x16x32_bf16(
                    af[m], bfr[n], acc[m][n], 0, 0, 0);
        __builtin_amdgcn_s_setprio(0);
        __builtin_amdgcn_s_barrier();

        // ---- phase B: A frags m4-7 (B reused); stage B(t+2)
#pragma unroll
        for (int m = 0; m < 4; ++m)
            af[m] = *(const short8v*)(sb + base_a + (m + 4) * 1024);
        GLDS(Bt + bsrc + (size_t)tn * GBK, sn + 16384 + ldst);
        GLDS(Bt + bsrc + (size_t)128 * K + (size_t)tn * GBK, sn + 16384 + 8192 + ldst);
        __builtin_amdgcn_s_setprio(1);
#pragma unroll
        for (int m = 0; m < 4; ++m)
#pragma unroll
            for (int n = 0; n < 4; ++n)
                acc[m + 4][n] = __builtin_amdgcn_mfma_f32_16x16x32_bf16(
                    af[m], bfr[n], acc[m + 4][n], 0, 0, 0);
        __builtin_amdgcn_s_setprio(0);
    }

    // ---- epilogue: plane select (uniform per block: BN=256 within one plane)
    int plane = n0 >> 9;   // 0..5
    unsigned short* dst;
    const float* bp;
    int stride;
    if      (plane == 0) { dst = P01F;     bp = nullptr;        stride = 2; }
    else if (plane == 1) { dst = P01F + 1; bp = bias_f;         stride = 2; }
    else if (plane == 2) { dst = P2F;      bp = bias_f + HDIM;  stride = 1; }
    else if (plane == 3) { dst = P01B;     bp = nullptr;        stride = 2; }
    else if (plane == 4) { dst = P01B + 1; bp = bias_b;         stride = 2; }
    else                 { dst = P2B;      bp = bias_b + HDIM;  stride = 1; }
    float smul = bp ? -L2E : 1.0f;
    int cip0 = (n0 & 511) + wc * 64;

    float tadd[4];
#pragma unroll
    for (int fn = 0; fn < 4; ++fn)
        tadd[fn] = bp ? -L2E * bp[cip0 + fn * 16 + l15] : 0.0f;

    // D[row=(l>>4)*4+j][col=l&15] per 16x16 frag (m89-verified layout)
#pragma unroll
    for (int fm = 0; fm < 8; ++fm) {
        int r0 = m0 + wr * 128 + fm * 16 + l4 * 4;
#pragma unroll
        for (int fn = 0; fn < 4; ++fn) {
            int chp = cip0 + fn * 16 + l15;
#pragma unroll
            for (int j = 0; j < 4; ++j)
                dst[((size_t)(r0 + j) * 512 + chp) * stride] =
                    f2bf(fmaf(smul, acc[fm][fn][j], tadd[fn]));
        }
    }
}

// ------------------------------ SRU scan -----------------------------------
// Both directions in one launch (grid.z = 2). Block = (64 ch) x (4 chunks);
// 4096 independent waves. Raw-bit rings, convert at consume. Warm ring
// issued FIRST (vmcnt completes in issue order). Streams: main {P01 dword,
// P2, xr} x DM=16 + warm {P01} x DW=8 -> peak 56 outstanding < 63 limit.
#define DM 16
#define DW 8
__global__ __launch_bounds__(256, 4) void sru_scan(
        const unsigned* __restrict__ P01f, const unsigned short* __restrict__ P2f,
        const unsigned* __restrict__ P01b, const unsigned short* __restrict__ P2b,
        const unsigned short* __restrict__ xrf, const unsigned short* __restrict__ xrb,
        const float* __restrict__ vF, const float* __restrict__ vB,
        unsigned short* __restrict__ hout) {
    int dir = blockIdx.z;
    int ch = blockIdx.x * 64 + threadIdx.x;
    int cid = blockIdx.y * 4 + threadIdx.y;

    const unsigned* P01;
    const unsigned short *P2, *xr;
    const float* vv;
    int outc;
    if (dir == 0) { P01 = P01f; P2 = P2f; xr = xrf; vv = vF; outc = ch; }
    else          { P01 = P01b; P2 = P2b; xr = xrb; vv = vB; outc = HDIM + ch; }

    float vfs = -L2E * vv[ch];
    float vrs = -L2E * vv[HDIM + ch];

    int cb = cid * CHUNK;
    int tstep = dir ? -1 : 1;
    int mstart = dir ? cb + CHUNK - 1 : cb;
    int wstart, wn;
    if (dir == 0) {
        wstart = cb - WARM; if (wstart < 0) wstart = 0;
        wn = cb - wstart;
    } else {
        wstart = cb + CHUNK - 1 + WARM; if (wstart > T_LEN - 1) wstart = T_LEN - 1;
        wn = wstart - (cb + CHUNK - 1);
    }

    // warm ring FIRST (oldest loads complete first)
    unsigned wr_[DW];
#pragma unroll
    for (int d = 0; d < DW; d++) {
        if (d < wn) {
            int t = wstart + tstep * d;
            wr_[d] = P01[(unsigned)t * 512u + ch];
        }
    }
    // main rings (hide under whole warm phase)
    unsigned a01[DM], a2[DM], axr[DM];
#pragma unroll
    for (int d = 0; d < DM; d++) {
        int t = mstart + tstep * d;
        unsigned bi = (unsigned)t * 512u + ch;
        a01[d] = P01[bi]; a2[d] = P2[bi];
        axr[d] = xr[(unsigned)t * 1024u + ch];
    }

    float c = 0.0f;
    // warm-up: state only (wn uniform across the wave)
    for (int nb = 0; nb < wn; nb += DW) {
#pragma unroll
        for (int d = 0; d < DW; d++) {
            int n = nb + d;
            if (n < wn) {
                unsigned p = wr_[d];
                float u0 = bf2f(p << 16 >> 16);
                float u1s = __uint_as_float(p & 0xffff0000u);
                int np = n + DW;
                if (np < wn) {
                    int tp = wstart + tstep * np;
                    wr_[d] = P01[(unsigned)tp * 512u + ch];
                }
                float g1 = sigm2(fmaf(vfs, c, u1s));
                c = u0 + g1 * (c - u0);
            }
        }
    }
    // main: full cell + h write (exactly CHUNK steps)
    for (int nb = 0; nb < CHUNK; nb += DM) {
#pragma unroll
        for (int d = 0; d < DM; d++) {
            int n = nb + d;
            int t = mstart + tstep * n;
            unsigned p = a01[d];
            float u0 = bf2f(p << 16 >> 16);
            float u1s = __uint_as_float(p & 0xffff0000u);
            float u2s = bf2f(a2[d]);
            float xv = bf2f(axr[d]);
            int np = n + DM;
            if (np < CHUNK) {
                int tp = mstart + tstep * np;
                unsigned bi = (unsigned)tp * 512u + ch;
                a01[d] = P01[bi]; a2[d] = P2[bi];
                axr[d] = xr[(unsigned)tp * 1024u + ch];
            }
            float g1 = sigm2(fmaf(vfs, c, u1s));
            c = u0 + g1 * (c - u0);
            float g2 = sigm2(fmaf(vrs, c, u2s));
            float h = xv + g2 * (c - xv);
            hout[(unsigned)t * 1024u + outc] = f2bf(h);
        }
    }
}

// ------------------------------ fc head ------------------------------------
__global__ __launch_bounds__(256) void fc_kernel(const unsigned short* __restrict__ h,
                                                 const float* __restrict__ W,
                                                 const float* __restrict__ bias,
                                                 float* __restrict__ out) {
    int gwid = (int)((blockIdx.x * (size_t)blockDim.x + threadIdx.x) >> 6);
    int lane = threadIdx.x & 63;
    int r0 = gwid * 4;
    int k0 = lane * 16;

    float hv[4][16];
#pragma unroll
    for (int r = 0; r < 4; r++) {
#pragma unroll
        for (int i = 0; i < 16; i += 8) {
            short8v v = *(const short8v*)(h + (size_t)(r0 + r) * D_IN + k0 + i);
#pragma unroll
            for (int j = 0; j < 8; j++)
                hv[r][i + j] = bf2f((unsigned short)v[j]);
        }
    }
    float acc[4][NC];
#pragma unroll
    for (int r = 0; r < 4; r++)
#pragma unroll
        for (int cdx = 0; cdx < NC; cdx++) acc[r][cdx] = 0.0f;

#pragma unroll
    for (int i = 0; i < 16; i++) {
        const float* wrow = W + (size_t)(k0 + i) * NC;
#pragma unroll
        for (int cdx = 0; cdx < NC; cdx++) {
            float wv = wrow[cdx];
            acc[0][cdx] += hv[0][i] * wv;
            acc[1][cdx] += hv[1][i] * wv;
            acc[2][cdx] += hv[2][i] * wv;
            acc[3][cdx] += hv[3][i] * wv;
        }
    }
#pragma unroll
    for (int r = 0; r < 4; r++)
#pragma unroll
        for (int cdx = 0; cdx < NC; cdx++) {
            float s = acc[r][cdx];
#pragma unroll
            for (int m = 1; m < 64; m <<= 1) s += __shfl_xor(s, m, 64);
            acc[r][cdx] = s;
        }
#pragma unroll
    for (int r = 0; r < 4; r++) {
        float val = 0.0f;
#pragma unroll
        for (int cdx = 0; cdx < NC; cdx++)
            if (lane == cdx) val = acc[r][cdx];
        if (lane < NC) out[(size_t)(r0 + r) * NC + lane] = val + bias[lane];
    }
}

// ------------------------------ launcher -----------------------------------
extern "C" void kernel_launch(void* const* d_in, const int* in_sizes, int n_in,
                              void* d_out, int out_size, void* d_ws, size_t ws_size,
                              hipStream_t stream) {
    const float* x    = (const float*)d_in[0];
    const float* w0f  = (const float*)d_in[1];
    const float* v0f  = (const float*)d_in[2];
    const float* b0f  = (const float*)d_in[3];
    const float* w0b  = (const float*)d_in[4];
    const float* v0b  = (const float*)d_in[5];
    const float* b0b  = (const float*)d_in[6];
    const float* w1f  = (const float*)d_in[7];
    const float* v1f  = (const float*)d_in[8];
    const float* b1f  = (const float*)d_in[9];
    const float* w1b  = (const float*)d_in[10];
    const float* v1b  = (const float*)d_in[11];
    const float* b1b  = (const float*)d_in[12];
    const float* fcw  = (const float*)d_in[13];
    const float* fcb  = (const float*)d_in[14];
    float* out = (float*)d_out;

    char* ws = (char*)d_ws;
    const size_t XB_B  = (size_t)T_LEN * D_IN * 2;    // 33.5 MB (also h1)
    const size_t WT_B  = (size_t)NU2 * D_IN * 2;      // 6.3 MB per layer
    const size_t H0_B  = (size_t)T_LEN * D_IN * 2;    // 33.5 MB
    const size_t P01_B = (size_t)T_LEN * HDIM * 4;    // 33.5 MB per dir
    const size_t P2_B  = (size_t)T_LEN * HDIM * 2;    // 16.8 MB per dir

    size_t off = 0;
    unsigned short* xb   = (unsigned short*)(ws + off); off += XB_B;
    unsigned short* h1   = xb;                            // alias: xb dead after layer-0 scan
    unsigned short* wt0  = (unsigned short*)(ws + off); off += WT_B;
    unsigned short* wt1  = (unsigned short*)(ws + off); off += WT_B;
    unsigned short* h0   = (unsigned short*)(ws + off); off += H0_B;
    unsigned short* P01F = (unsigned short*)(ws + off); off += P01_B;
    unsigned short* P2F  = (unsigned short*)(ws + off); off += P2_B;
    unsigned short* P01B = (unsigned short*)(ws + off); off += P01_B;
    unsigned short* P2B  = (unsigned short*)(ws + off); off += P2_B;
    // total ~180.5 MB — same footprint class as rounds 3-8 (fit).

    // 1. casts / transposes
    cast_f32_bf16<<<T_LEN * D_IN / 4 / 256, 256, 0, stream>>>(x, xb, (long)T_LEN * D_IN);
    dim3 tb(32, 8);
    dim3 tg(1536 / 32, D_IN / 32);
    transpose_cast<<<tg, tb, 0, stream>>>(w0f, wt0, D_IN, 1536);
    transpose_cast<<<tg, tb, 0, stream>>>(w0b, wt0 + (size_t)1536 * D_IN, D_IN, 1536);
    transpose_cast<<<tg, tb, 0, stream>>>(w1f, wt1, D_IN, 1536);
    transpose_cast<<<tg, tb, 0, stream>>>(w1b, wt1 + (size_t)1536 * D_IN, D_IN, 1536);

    dim3 gg((T_LEN / GBM) * (NU2 / GBN));   // 64*12 = 768 blocks, swizzled in-kernel
    dim3 sg(HDIM / 64, NCHUNK / 4, 2);
    dim3 sb(64, 4, 1);

    // 2. layer 0 (x_res read from xb, bf16)
    gemm_pipe<<<gg, 512, 4 * SLOT_B, stream>>>(xb, wt0, P01F, P2F, P01B, P2B, b0f, b0b);
    sru_scan<<<sg, sb, 0, stream>>>((const unsigned*)P01F, P2F, (const unsigned*)P01B, P2B,
                                    xb, xb + HDIM, v0f, v0b, h0);

    // 3. layer 1 (h1 aliases xb; xb no longer read after layer-0 scan)
    gemm_pipe<<<gg, 512, 4 * SLOT_B, stream>>>(h0, wt1, P01F, P2F, P01B, P2B, b1f, b1b);
    sru_scan<<<sg, sb, 0, stream>>>((const unsigned*)P01F, P2F, (const unsigned*)P01B, P2B,
                                    h0, h0 + HDIM, v1f, v1b, h1);

    // 4. fc head
    fc_kernel<<<T_LEN / 4 * 64 / 256, 256, 0, stream>>>(h1, fcw, fcb, out);
    (void)in_sizes; (void)n_in; (void)out_size;
}

// Round 10
// 357.782 us; speedup vs baseline: 5.0345x; 1.0224x over previous
//
#include <hip/hip_runtime.h>

// ---------------------------------------------------------------------------
// SRU (2-layer bidirectional, v2 cell) + fc head for MI355X (gfx950).
//   1. cast x (f32 -> bf16)
//   2. transpose+cast weights into ONE concatenated Wt[3072][1024] per layer,
//      with u0/u1 rows INTERLEAVED in 16-channel strips (so the GEMM can emit
//      packed u0|u1' dwords); u2 rows kept contiguous.
//   3. per layer: ONE fused 256x256-tile pipelined GEMM (8 waves, 4-slot LDS
//      ring, counted vmcnt(4), setprio MFMA clusters) writing P01 (dword
//      u0 | -L2E*(u1+bf)) and P2 (-L2E*(u2+br)) per direction
//   4. one scan launch per layer (both dirs; 56 outstanding loads < 63 vmcnt
//      limit), then fc head
// ---------------------------------------------------------------------------

#define T_LEN 16384
#define D_IN 1024
#define HDIM 512
#define NC 15
#define NU2 3072         // both directions' 3*H columns
#define CHUNK 64
#define WARM 64
#define NCHUNK (T_LEN / CHUNK)   // 256
#define L2E 1.44269504f

typedef __attribute__((ext_vector_type(8))) short short8v;
typedef __attribute__((ext_vector_type(4))) float float4v;
typedef __attribute__((ext_vector_type(4))) int int4v;

__device__ __forceinline__ unsigned short f2bf(float f) {
    unsigned u = __float_as_uint(f);
    unsigned r = (u + 0x7FFFu + ((u >> 16) & 1u)) >> 16;
    return (unsigned short)r;
}
__device__ __forceinline__ float bf2f(unsigned s) {
    return __uint_as_float(s << 16);
}
__device__ __forceinline__ float sigm2(float zarg) {   // 1/(1+2^zarg)
    float e = __builtin_amdgcn_exp2f(zarg);
    return __builtin_amdgcn_rcpf(1.0f + e);
}

// async global->LDS, 16 B/lane; LDS dest = wave-uniform base + lane*16
#define GLDS(gp, lp)                                                          \
    __builtin_amdgcn_global_load_lds(                                         \
        (const __attribute__((address_space(1))) unsigned int*)(gp),          \
        (__attribute__((address_space(3))) unsigned int*)(lp), 16, 0, 0)

// -------------------------- cast x to bf16 ---------------------------------
__global__ __launch_bounds__(256) void cast_f32_bf16(const float* __restrict__ in,
                                                     unsigned short* __restrict__ out,
                                                     long n) {
    long i = ((long)blockIdx.x * blockDim.x + threadIdx.x) * 4;
    if (i + 3 < n) {
        float4v v = *(const float4v*)(in + i);
        unsigned short o0 = f2bf(v[0]), o1 = f2bf(v[1]), o2 = f2bf(v[2]), o3 = f2bf(v[3]);
        unsigned short* p = out + i;
        p[0] = o0; p[1] = o1; p[2] = o2; p[3] = o3;
    }
}

// -------- transpose + cast + permute: W[1024][1536] f32 -> Wt[1536][1024] --
// Output row n (0..1535):
//   n < 1024 : srccol = ((n>>4)&1)*512 + (n>>5)*16 + (n&15)   (u0/u1 interleave)
//   n >= 1024: srccol = n                                      (u2 identity)
__global__ __launch_bounds__(256) void transpose_perm(const float* __restrict__ w,
                                                      unsigned short* __restrict__ wt) {
    __shared__ float tile[32][33];
    const int K = 1024, N = 1536;
    int n0 = blockIdx.x * 32, k0 = blockIdx.y * 32;
    int tx = threadIdx.x;   // 0..31
    int ty = threadIdx.y;   // 0..7
    // source column for output row n0+tx (n0 is a multiple of 32)
    int sc;
    if (n0 < 1024) sc = (tx >> 4) * 512 + (n0 >> 1) + (tx & 15);
    else           sc = n0 + tx;
#pragma unroll
    for (int i = 0; i < 32; i += 8)
        tile[ty + i][tx] = w[(size_t)(k0 + ty + i) * N + sc];
    __syncthreads();
#pragma unroll
    for (int i = 0; i < 32; i += 8)
        wt[(size_t)(n0 + ty + i) * K + k0 + tx] = f2bf(tile[tx][ty + i]);
}

// ------------------------- pipelined 256x256 GEMM --------------------------
// U[M][3072] = A[M][1024] bf16 @ Wt[3072][1024] bf16.
// 512 thr = 8 waves (2 M x 4 N), per-wave 128x64 out = acc[8][4] 16x16 frags.
// K-tile = BK=32. LDS ring: 4 slots x (A 16KB + B 16KB) = 128 KB.
// Counted vmcnt(4) + s_barrier at K-tile top; stage distance 2; setprio
// around MFMA clusters. Swizzle: LDS[r][c'] = global chunk c'^(r&3)^((r>>2)&3)
// via pre-swizzled global src + linear GLDS dest + swizzled ds_read.
// Epilogue: section tiles nX<1024 are u0/u1 pair tiles -> packed dword P01
// stores (frag pairs (0,1),(2,3) hold u0/u1 of the SAME channels); nX>=1024
// are u2 tiles -> unit-stride ushort P2 stores.
#define GBM 256
#define GBN 256
#define GBK 32
#define SLOT_B 32768     // A 16KB + B 16KB per slot

__global__ __launch_bounds__(512, 2) void gemm_pipe(const unsigned short* __restrict__ A,
                                                    const unsigned short* __restrict__ Bt,
                                                    unsigned* __restrict__ P01F,
                                                    unsigned short* __restrict__ P2F,
                                                    unsigned* __restrict__ P01B,
                                                    unsigned short* __restrict__ P2B,
                                                    const float* __restrict__ bias_f,
                                                    const float* __restrict__ bias_b) {
    extern __shared__ char smem[];
    const int K = 1024;

    int tid = threadIdx.x;
    // XCD swizzle: 768 blocks, XCD k owns m-tiles [8k,8k+8); n outer, m inner
    int h = blockIdx.x;
    int w = (h & 7) * 96 + (h >> 3);
    int xcd = w / 96, lw = w % 96;
    int m0 = (xcd * 8 + (lw & 7)) * GBM;
    int n0 = (lw >> 3) * GBN;

    int wid = tid >> 6, lane = tid & 63;
    int wr = wid >> 2, wc = wid & 3;
    int l15 = lane & 15, l4 = lane >> 4;

    // staging source (per-thread): row-in-tile rr, swizzled chunk cs (elements)
    int rr = tid >> 2;
    int cs = (((tid & 3) ^ (rr & 3) ^ ((rr >> 2) & 3)) << 3);
    size_t asrc = (size_t)(m0 + rr) * K + cs;
    size_t bsrc = (size_t)(n0 + rr) * K + cs;
    int ldst = wid << 10;                 // wave-uniform LDS byte base (+lane*16 by HW)

    // ds_read bases: chunkoff constant per lane across all frags
    int chko = ((l4 ^ (l15 & 3) ^ ((l15 >> 2) & 3)) << 4);
    int base_a = (wr * 128 + l15) * 64 + chko;            // in A region
    int base_b = 16384 + (wc * 64 + l15) * 64 + chko;     // in B region

    // prologue: stage K-tiles 0,1 into slots 0,1 (A then B per tile)
#pragma unroll
    for (int t = 0; t < 2; ++t) {
        char* sb = smem + t * SLOT_B;
        GLDS(A + asrc + (size_t)t * GBK, sb + ldst);
        GLDS(A + asrc + (size_t)128 * K + (size_t)t * GBK, sb + 8192 + ldst);
        GLDS(Bt + bsrc + (size_t)t * GBK, sb + 16384 + ldst);
        GLDS(Bt + bsrc + (size_t)128 * K + (size_t)t * GBK, sb + 16384 + 8192 + ldst);
    }

    float4v acc[8][4] = {};
    short8v bfr[4], af[4];

    for (int t = 0; t < 32; ++t) {
        asm volatile("s_waitcnt vmcnt(4)" ::: "memory");
        __builtin_amdgcn_s_barrier();
        char* sb = smem + (t & 3) * SLOT_B;
        int tn = (t + 2) & 31;                   // wrap: stale-slot restage keeps count uniform
        char* sn = smem + (tn & 3) * SLOT_B;

        // ---- phase A: B frags n0-3, A frags m0-3; stage A(t+2)
#pragma unroll
        for (int n = 0; n < 4; ++n)
            bfr[n] = *(const short8v*)(sb + base_b + n * 1024);
#pragma unroll
        for (int m = 0; m < 4; ++m)
            af[m] = *(const short8v*)(sb + base_a + m * 1024);
        GLDS(A + asrc + (size_t)tn * GBK, sn + ldst);
        GLDS(A + asrc + (size_t)128 * K + (size_t)tn * GBK, sn + 8192 + ldst);
        __builtin_amdgcn_s_setprio(1);
#pragma unroll
        for (int m = 0; m < 4; ++m)
#pragma unroll
            for (int n = 0; n < 4; ++n)
                acc[m][n] = __builtin_amdgcn_mfma_f32_16x16x32_bf16(
                    af[m], bfr[n], acc[m][n], 0, 0, 0);
        __builtin_amdgcn_s_setprio(0);
        __builtin_amdgcn_s_barrier();

        // ---- phase B: A frags m4-7 (B reused); stage B(t+2)
#pragma unroll
        for (int m = 0; m < 4; ++m)
            af[m] = *(const short8v*)(sb + base_a + (m + 4) * 1024);
        GLDS(Bt + bsrc + (size_t)tn * GBK, sn + 16384 + ldst);
        GLDS(Bt + bsrc + (size_t)128 * K + (size_t)tn * GBK, sn + 16384 + 8192 + ldst);
        __builtin_amdgcn_s_setprio(1);
#pragma unroll
        for (int m = 0; m < 4; ++m)
#pragma unroll
            for (int n = 0; n < 4; ++n)
                acc[m + 4][n] = __builtin_amdgcn_mfma_f32_16x16x32_bf16(
                    af[m], bfr[n], acc[m + 4][n], 0, 0, 0);
        __builtin_amdgcn_s_setprio(0);
    }

    // ---- epilogue (D[row=(l>>4)*4+j][col=l&15] per frag, m89-verified) ----
    int sec = (n0 >= 1536) ? 1 : 0;          // 0 = fwd, 1 = bwd
    int nX = n0 - sec * 1536;                // 0..1535 within section
    const float* bias = sec ? bias_b : bias_f;

    if (nX < 1024) {
        // pair tile: frag pairs (0,1),(2,3) = u0,u1 of the same channels
        unsigned* dst = sec ? P01B : P01F;
#pragma unroll
        for (int fp = 0; fp < 2; ++fp) {
            int ch = (nX >> 1) + wc * 32 + fp * 16 + l15;
            float bv = -L2E * bias[ch];
#pragma unroll
            for (int fm = 0; fm < 8; ++fm) {
                int r0 = m0 + wr * 128 + fm * 16 + l4 * 4;
#pragma unroll
                for (int j = 0; j < 4; ++j) {
                    unsigned lo = f2bf(acc[fm][2 * fp][j]);
                    unsigned hi = f2bf(fmaf(-L2E, acc[fm][2 * fp + 1][j], bv));
                    dst[(size_t)(r0 + j) * 512 + ch] = lo | (hi << 16);
                }
            }
        }
    } else {
        // u2 tile: unit-stride ushort stores
        unsigned short* dst = sec ? P2B : P2F;
#pragma unroll
        for (int fn = 0; fn < 4; ++fn) {
            int ch = (nX - 1024) + wc * 64 + fn * 16 + l15;
            float bv = -L2E * bias[512 + ch];
#pragma unroll
            for (int fm = 0; fm < 8; ++fm) {
                int r0 = m0 + wr * 128 + fm * 16 + l4 * 4;
#pragma unroll
                for (int j = 0; j < 4; ++j)
                    dst[(size_t)(r0 + j) * 512 + ch] =
                        f2bf(fmaf(-L2E, acc[fm][fn][j], bv));
            }
        }
    }
}

// ------------------------------ SRU scan -----------------------------------
// Both directions in one launch (grid.z = 2). Block = (64 ch) x (4 chunks);
// 4096 independent waves. Raw-bit rings, convert at consume. Warm ring
// issued FIRST (vmcnt completes in issue order). Streams: main {P01 dword,
// P2, xr} x DM=16 + warm {P01} x DW=8 -> peak 56 outstanding < 63 limit.
#define DM 16
#define DW 8
__global__ __launch_bounds__(256, 4) void sru_scan(
        const unsigned* __restrict__ P01f, const unsigned short* __restrict__ P2f,
        const unsigned* __restrict__ P01b, const unsigned short* __restrict__ P2b,
        const unsigned short* __restrict__ xrf, const unsigned short* __restrict__ xrb,
        const float* __restrict__ vF, const float* __restrict__ vB,
        unsigned short* __restrict__ hout) {
    int dir = blockIdx.z;
    int ch = blockIdx.x * 64 + threadIdx.x;
    int cid = blockIdx.y * 4 + threadIdx.y;

    const unsigned* P01;
    const unsigned short *P2, *xr;
    const float* vv;
    int outc;
    if (dir == 0) { P01 = P01f; P2 = P2f; xr = xrf; vv = vF; outc = ch; }
    else          { P01 = P01b; P2 = P2b; xr = xrb; vv = vB; outc = HDIM + ch; }

    float vfs = -L2E * vv[ch];
    float vrs = -L2E * vv[HDIM + ch];

    int cb = cid * CHUNK;
    int tstep = dir ? -1 : 1;
    int mstart = dir ? cb + CHUNK - 1 : cb;
    int wstart, wn;
    if (dir == 0) {
        wstart = cb - WARM; if (wstart < 0) wstart = 0;
        wn = cb - wstart;
    } else {
        wstart = cb + CHUNK - 1 + WARM; if (wstart > T_LEN - 1) wstart = T_LEN - 1;
        wn = wstart - (cb + CHUNK - 1);
    }

    // warm ring FIRST (oldest loads complete first)
    unsigned wr_[DW];
#pragma unroll
    for (int d = 0; d < DW; d++) {
        if (d < wn) {
            int t = wstart + tstep * d;
            wr_[d] = P01[(unsigned)t * 512u + ch];
        }
    }
    // main rings (hide under whole warm phase)
    unsigned a01[DM], a2[DM], axr[DM];
#pragma unroll
    for (int d = 0; d < DM; d++) {
        int t = mstart + tstep * d;
        unsigned bi = (unsigned)t * 512u + ch;
        a01[d] = P01[bi]; a2[d] = P2[bi];
        axr[d] = xr[(unsigned)t * 1024u + ch];
    }

    float c = 0.0f;
    // warm-up: state only (wn uniform across the wave)
    for (int nb = 0; nb < wn; nb += DW) {
#pragma unroll
        for (int d = 0; d < DW; d++) {
            int n = nb + d;
            if (n < wn) {
                unsigned p = wr_[d];
                float u0 = bf2f(p << 16 >> 16);
                float u1s = __uint_as_float(p & 0xffff0000u);
                int np = n + DW;
                if (np < wn) {
                    int tp = wstart + tstep * np;
                    wr_[d] = P01[(unsigned)tp * 512u + ch];
                }
                float g1 = sigm2(fmaf(vfs, c, u1s));
                c = u0 + g1 * (c - u0);
            }
        }
    }
    // main: full cell + h write (exactly CHUNK steps)
    for (int nb = 0; nb < CHUNK; nb += DM) {
#pragma unroll
        for (int d = 0; d < DM; d++) {
            int n = nb + d;
            int t = mstart + tstep * n;
            unsigned p = a01[d];
            float u0 = bf2f(p << 16 >> 16);
            float u1s = __uint_as_float(p & 0xffff0000u);
            float u2s = bf2f(a2[d]);
            float xv = bf2f(axr[d]);
            int np = n + DM;
            if (np < CHUNK) {
                int tp = mstart + tstep * np;
                unsigned bi = (unsigned)tp * 512u + ch;
                a01[d] = P01[bi]; a2[d] = P2[bi];
                axr[d] = xr[(unsigned)tp * 1024u + ch];
            }
            float g1 = sigm2(fmaf(vfs, c, u1s));
            c = u0 + g1 * (c - u0);
            float g2 = sigm2(fmaf(vrs, c, u2s));
            float h = xv + g2 * (c - xv);
            hout[(unsigned)t * 1024u + outc] = f2bf(h);
        }
    }
}

// ------------------------------ fc head ------------------------------------
__global__ __launch_bounds__(256) void fc_kernel(const unsigned short* __restrict__ h,
                                                 const float* __restrict__ W,
                                                 const float* __restrict__ bias,
                                                 float* __restrict__ out) {
    int gwid = (int)((blockIdx.x * (size_t)blockDim.x + threadIdx.x) >> 6);
    int lane = threadIdx.x & 63;
    int r0 = gwid * 4;
    int k0 = lane * 16;

    float hv[4][16];
#pragma unroll
    for (int r = 0; r < 4; r++) {
#pragma unroll
        for (int i = 0; i < 16; i += 8) {
            short8v v = *(const short8v*)(h + (size_t)(r0 + r) * D_IN + k0 + i);
#pragma unroll
            for (int j = 0; j < 8; j++)
                hv[r][i + j] = bf2f((unsigned short)v[j]);
        }
    }
    float acc[4][NC];
#pragma unroll
    for (int r = 0; r < 4; r++)
#pragma unroll
        for (int cdx = 0; cdx < NC; cdx++) acc[r][cdx] = 0.0f;

#pragma unroll
    for (int i = 0; i < 16; i++) {
        const float* wrow = W + (size_t)(k0 + i) * NC;
#pragma unroll
        for (int cdx = 0; cdx < NC; cdx++) {
            float wv = wrow[cdx];
            acc[0][cdx] += hv[0][i] * wv;
            acc[1][cdx] += hv[1][i] * wv;
            acc[2][cdx] += hv[2][i] * wv;
            acc[3][cdx] += hv[3][i] * wv;
        }
    }
#pragma unroll
    for (int r = 0; r < 4; r++)
#pragma unroll
        for (int cdx = 0; cdx < NC; cdx++) {
            float s = acc[r][cdx];
#pragma unroll
            for (int m = 1; m < 64; m <<= 1) s += __shfl_xor(s, m, 64);
            acc[r][cdx] = s;
        }
#pragma unroll
    for (int r = 0; r < 4; r++) {
        float val = 0.0f;
#pragma unroll
        for (int cdx = 0; cdx < NC; cdx++)
            if (lane == cdx) val = acc[r][cdx];
        if (lane < NC) out[(size_t)(r0 + r) * NC + lane] = val + bias[lane];
    }
}

// ------------------------------ launcher -----------------------------------
extern "C" void kernel_launch(void* const* d_in, const int* in_sizes, int n_in,
                              void* d_out, int out_size, void* d_ws, size_t ws_size,
                              hipStream_t stream) {
    const float* x    = (const float*)d_in[0];
    const float* w0f  = (const float*)d_in[1];
    const float* v0f  = (const float*)d_in[2];
    const float* b0f  = (const float*)d_in[3];
    const float* w0b  = (const float*)d_in[4];
    const float* v0b  = (const float*)d_in[5];
    const float* b0b  = (const float*)d_in[6];
    const float* w1f  = (const float*)d_in[7];
    const float* v1f  = (const float*)d_in[8];
    const float* b1f  = (const float*)d_in[9];
    const float* w1b  = (const float*)d_in[10];
    const float* v1b  = (const float*)d_in[11];
    const float* b1b  = (const float*)d_in[12];
    const float* fcw  = (const float*)d_in[13];
    const float* fcb  = (const float*)d_in[14];
    float* out = (float*)d_out;

    char* ws = (char*)d_ws;
    const size_t XB_B  = (size_t)T_LEN * D_IN * 2;    // 33.5 MB (also h1)
    const size_t WT_B  = (size_t)NU2 * D_IN * 2;      // 6.3 MB per layer
    const size_t H0_B  = (size_t)T_LEN * D_IN * 2;    // 33.5 MB
    const size_t P01_B = (size_t)T_LEN * HDIM * 4;    // 33.5 MB per dir
    const size_t P2_B  = (size_t)T_LEN * HDIM * 2;    // 16.8 MB per dir

    size_t off = 0;
    unsigned short* xb   = (unsigned short*)(ws + off); off += XB_B;
    unsigned short* h1   = xb;                            // alias: xb dead after layer-0 scan
    unsigned short* wt0  = (unsigned short*)(ws + off); off += WT_B;
    unsigned short* wt1  = (unsigned short*)(ws + off); off += WT_B;
    unsigned short* h0   = (unsigned short*)(ws + off); off += H0_B;
    unsigned*       P01F = (unsigned*)(ws + off);       off += P01_B;
    unsigned short* P2F  = (unsigned short*)(ws + off); off += P2_B;
    unsigned*       P01B = (unsigned*)(ws + off);       off += P01_B;
    unsigned short* P2B  = (unsigned short*)(ws + off); off += P2_B;
    // total ~180.5 MB — same footprint class as rounds 3-9 (fit).

    // 1. casts / transposes (permuted: u0/u1 interleaved, u2 identity)
    cast_f32_bf16<<<T_LEN * D_IN / 4 / 256, 256, 0, stream>>>(x, xb, (long)T_LEN * D_IN);
    dim3 tb(32, 8);
    dim3 tg(1536 / 32, D_IN / 32);
    transpose_perm<<<tg, tb, 0, stream>>>(w0f, wt0);
    transpose_perm<<<tg, tb, 0, stream>>>(w0b, wt0 + (size_t)1536 * D_IN);
    transpose_perm<<<tg, tb, 0, stream>>>(w1f, wt1);
    transpose_perm<<<tg, tb, 0, stream>>>(w1b, wt1 + (size_t)1536 * D_IN);

    dim3 gg((T_LEN / GBM) * (NU2 / GBN));   // 64*12 = 768 blocks, swizzled in-kernel
    dim3 sg(HDIM / 64, NCHUNK / 4, 2);
    dim3 sb(64, 4, 1);

    // 2. layer 0 (x_res read from xb, bf16)
    gemm_pipe<<<gg, 512, 4 * SLOT_B, stream>>>(xb, wt0, P01F, P2F, P01B, P2B, b0f, b0b);
    sru_scan<<<sg, sb, 0, stream>>>(P01F, P2F, P01B, P2B,
                                    xb, xb + HDIM, v0f, v0b, h0);

    // 3. layer 1 (h1 aliases xb; xb no longer read after layer-0 scan)
    gemm_pipe<<<gg, 512, 4 * SLOT_B, stream>>>(h0, wt1, P01F, P2F, P01B, P2B, b1f, b1b);
    sru_scan<<<sg, sb, 0, stream>>>(P01F, P2F, P01B, P2B,
                                    h0, h0 + HDIM, v1f, v1b, h1);

    // 4. fc head
    fc_kernel<<<T_LEN / 4 * 64 / 256, 256, 0, stream>>>(h1, fcw, fcb, out);
    (void)in_sizes; (void)n_in; (void)out_size;
}